// Round 15
// baseline (360.841 us; speedup 1.0000x reference)
//
#include <hip/hip_runtime.h>

#define NSRC 784
#define NTOT 1568
#define NHD 8
#define DVC 256
#define DCC 64
#define D20 20
#define FDIM 512
#define OUT_PER_SRC 25690112

typedef short s16x8 __attribute__((ext_vector_type(8)));
typedef unsigned short u16x8 __attribute__((ext_vector_type(8)));
typedef unsigned short u16x4 __attribute__((ext_vector_type(4)));
typedef float f32x4 __attribute__((ext_vector_type(4)));
typedef float f32x16 __attribute__((ext_vector_type(16)));
typedef unsigned u32x4 __attribute__((ext_vector_type(4)));

#define LOG2E 1.4426950408889634f

__device__ __forceinline__ unsigned short f2bf(float x) {
    unsigned u = __float_as_uint(x);
    unsigned r = (u + 0x7FFFu + ((u >> 16) & 1u)) >> 16;   // RNE
    return (unsigned short)r;
}

__device__ __forceinline__ unsigned cvt_pk_bf16(float lo, float hi) {
    unsigned r;
    asm volatile("v_cvt_pk_bf16_f32 %0, %1, %2" : "=v"(r) : "v"(lo), "v"(hi));
    return r;
}

// native 2^x (single v_exp_f32, no libcall guards, no pre-multiply)
__device__ __forceinline__ float fexp2(float x) {
    float r;
    asm("v_exp_f32 %0, %1" : "=v"(r) : "v"(x));
    return r;
}

// split float into bf16 hi + bf16 lo correction (x ~= hi + lo)
__device__ __forceinline__ void split_bf(float x, unsigned short& hi, unsigned short& lo) {
    unsigned short h = f2bf(x);
    float hf = __uint_as_float(((unsigned)h) << 16);
    hi = h;
    lo = f2bf(x - hf);
}

// v_permlane32_swap_b32: a' = [a.lo32 | b.lo32], b' = [a.hi32 | b.hi32]
__device__ __forceinline__ void permlane32_swap(unsigned& a, unsigned& b) {
    asm volatile("v_permlane32_swap_b32 %0, %1" : "+v"(a), "+v"(b));
}

// ---------------------------------------------------------------------------
// KZ: zero Qp+Kp (contiguous) — clears the d in [20,32) pad slots
__global__ __launch_bounds__(256) void kz_zero(unsigned short* __restrict__ p) {
    size_t i = (size_t)blockIdx.x * 256 + threadIdx.x;
    u16x8 z = (u16x8)0;
    *(u16x8*)&p[i * 8] = z;
}

// ---------------------------------------------------------------------------
// K0c: pack Wv(256dd x 64e) -> A-fragment order hi/lo for k3
__global__ __launch_bounds__(256) void k0c_wvpack(
    const float* __restrict__ Wv, unsigned short* __restrict__ Wvp) {
    int idx = blockIdx.x * 256 + threadIdx.x;        // 0..65535
    int j = idx & 7, lane = (idx >> 3) & 63, hl = (idx >> 9) & 1;
    int c = (idx >> 10) & 7, mi = idx >> 13;
    int e = mi * 16 + (lane & 15);
    int dd = c * 32 + (lane >> 4) * 8 + j;
    unsigned short h, l;
    split_bf(Wv[dd * DCC + e], h, l);
    Wvp[idx] = hl ? l : h;
}

// ---------------------------------------------------------------------------
// K0b: pack Wback(64j x 256c) -> A-fragment order hi/lo
__global__ __launch_bounds__(256) void k0b_wback(
    const float* __restrict__ Wb, unsigned short* __restrict__ Wp) {
    int idx = blockIdx.x * 256 + threadIdx.x;        // 0..65535
    int jj = idx & 7, lane = (idx >> 3) & 63, hl = (idx >> 9) & 1;
    int kc = (idx >> 10) & 1, mt = idx >> 11;
    int c = mt * 16 + (lane & 15);
    int j = kc * 32 + (lane >> 4) * 8 + jj;
    unsigned short h, l;
    split_bf(Wb[j * 256 + c], h, l);
    Wp[idx] = hl ? l : h;
}

// ---------------------------------------------------------------------------
// K1c: window average of coords only
__global__ __launch_bounds__(256) void k1c_avg(
    const float* __restrict__ c0, const float* __restrict__ c1,
    float* __restrict__ Cavg) {
    int wi = blockIdx.x * 4 + (threadIdx.x >> 6);
    int d = threadIdx.x & 63;
    int b = wi / NTOT, N = wi % NTOT;
    int src = N / NSRC, nloc = N % NSRC;
    int wh = nloc / 28, ww = nloc % 28;
    const float* __restrict__ C = src ? c1 : c0;
    int pbase = (b * 224 + wh * 8) * 224 + ww * 8;
    float s = 0.f;
#pragma unroll 8
    for (int p = 0; p < 64; ++p)
        s += C[(size_t)(pbase + (p >> 3) * 224 + (p & 7)) * DCC + d];
    Cavg[(size_t)wi * DCC + d] = s * 0.015625f;
}

// ---------------------------------------------------------------------------
// K2: qk = rmsnorm(avg @ Wqk + b, g); writes Q/K bf16 hi/lo fragments in
// k4's packed lane order. Q pre-scaled by log2(e)/sqrt(I) -> exp2 softmax.
__global__ __launch_bounds__(256) void k2_qk(
    const float* __restrict__ Vavg, const float* __restrict__ Cavg,
    const float* __restrict__ Wqkv, const float* __restrict__ bqkv, const float* __restrict__ gv,
    const float* __restrict__ Wqkc, const float* __restrict__ bqkc, const float* __restrict__ gc,
    unsigned short* __restrict__ Qp, unsigned short* __restrict__ Kp) {
    __shared__ float xv[DVC];
    __shared__ float xc[DCC];
    __shared__ float wred[4];
    int blk = blockIdx.x;
    int b = blk / NTOT, N = blk % NTOT;
    int t = threadIdx.x;
    int tile = N >> 5, l31 = N & 31;
    xv[t] = Vavg[(size_t)blk * DVC + t];
    if (t < DCC) xc[t] = Cavg[(size_t)blk * DCC + t];
    __syncthreads();
    float yv = bqkv[t];
#pragma unroll 4
    for (int d = 0; d < DVC; ++d) yv += xv[d] * Wqkv[d * 256 + t];
    float ss = yv * yv;
#pragma unroll
    for (int off = 32; off; off >>= 1) ss += __shfl_xor(ss, off, 64);
    if ((t & 63) == 0) wred[t >> 6] = ss;
    __syncthreads();
    float tot = wred[0] + wred[1] + wred[2] + wred[3];
    float rv = rsqrtf(tot * (1.f / 256.f) + 1e-6f);
    float yn = yv * rv * gv[t];
    int h = t >> 5, c = t & 31;
    int bh = b * NHD + h;
    {
        int isq = (c < 16);
        int d = isq ? c : c - 16;
        float val = isq ? yn * (0.088388347648318447f * LOG2E) : yn;
        unsigned short h16, l16;
        split_bf(val, h16, l16);
        int hh = d >> 3, j = d & 7;
        size_t base = ((size_t)(bh * 49 + tile) * 4) * 512 + (size_t)(hh * 32 + l31) * 8 + j;
        unsigned short* dst = isq ? Qp : Kp;
        dst[base] = h16;
        dst[base + 1024] = l16;
    }
    if (t < DCC) {
        float yc = bqkc[t];
#pragma unroll 4
        for (int d = 0; d < DCC; ++d) yc += xc[d] * Wqkc[d * 64 + t];
        float sc = yc * yc;
#pragma unroll
        for (int off = 32; off; off >>= 1) sc += __shfl_xor(sc, off, 64);
        float rc = rsqrtf(sc * (1.f / 64.f) + 1e-6f);
        float ycn = yc * rc * gc[t];
        int h2 = t >> 3, c2 = t & 7;
        int bh2 = b * NHD + h2;
        int isq = (c2 < 4);
        int dd = isq ? c2 : c2 - 4;
        float val = isq ? ycn * (0.17677669529663687f * LOG2E) : ycn;
        unsigned short h16, l16;
        split_bf(val, h16, l16);
        size_t base = ((size_t)(bh2 * 49 + tile) * 4 + 1) * 512 + (size_t)l31 * 8 + dd;
        unsigned short* dst = isq ? Qp : Kp;
        dst[base] = h16;
        dst[base + 1024] = l16;
    }
}

// ---------------------------------------------------------------------------
// K3: per-window GEMM as D[e][px] = W^T @ X^T — zero-LDS, zero-barrier main
// loop. (unchanged from R10)
__global__ __launch_bounds__(256) void k3_vv(
    const float* __restrict__ v0, const float* __restrict__ v1,
    const unsigned short* __restrict__ Wvp,
    unsigned short* __restrict__ Vvb, float* __restrict__ Vavg) {
    __shared__ unsigned short eb[64 * 66];   // 8.4 KB
    __shared__ float avgw[1024];             // 4 KB
    int blk = blockIdx.x;
    int b = blk / NTOT, N = blk % NTOT;
    int src = N / NSRC, nloc = N % NSRC;
    int wh = nloc / 28, ww = nloc % 28;
    const float* __restrict__ V = src ? v1 : v0;
    int t = threadIdx.x;
    int w = t >> 6, lane = t & 63;
    int lm = lane & 15, lk = lane >> 4;
    int px = w * 16 + lm;
    int pbase = (b * 224 + wh * 8) * 224 + ww * 8;
    const float* __restrict__ xrow =
        V + (size_t)(pbase + (px >> 3) * 224 + (px & 7)) * DVC + lk * 8;

    f32x4 acc[4];
#pragma unroll
    for (int mi = 0; mi < 4; ++mi) acc[mi] = (f32x4)0.f;

#pragma unroll
    for (int c = 0; c < 8; ++c) {
        float4 x0 = *(const float4*)&xrow[c * 32];
        float4 x1 = *(const float4*)&xrow[c * 32 + 4];
        float xv8[8] = {x0.x, x0.y, x0.z, x0.w, x1.x, x1.y, x1.z, x1.w};
        u16x8 bhu, blu;
#pragma unroll
        for (int j = 0; j < 8; ++j) {
            unsigned short hq, lq;
            split_bf(xv8[j], hq, lq);
            bhu[j] = hq; blu[j] = lq;
        }
        s16x8 xhi = __builtin_bit_cast(s16x8, bhu);
        s16x8 xlo = __builtin_bit_cast(s16x8, blu);
        float sv[8] = {xv8[0], xv8[1], xv8[2], xv8[3], xv8[4], xv8[5], xv8[6], xv8[7]};
#pragma unroll
        for (int off = 1; off <= 8; off <<= 1)
#pragma unroll
            for (int j = 0; j < 8; ++j) sv[j] += __shfl_xor(sv[j], off, 64);
        if (lm == 0) {
#pragma unroll
            for (int j = 0; j < 8; ++j)
                avgw[w * 256 + c * 32 + lk * 8 + j] = sv[j];
        }
#pragma unroll
        for (int mi = 0; mi < 4; ++mi) {
            const unsigned short* Wf = Wvp + (size_t)((mi * 8 + c) * 2) * 512 + lane * 8;
            s16x8 Ah = *(const s16x8*)&Wf[0];
            s16x8 Al = *(const s16x8*)&Wf[512];
            acc[mi] = __builtin_amdgcn_mfma_f32_16x16x32_bf16(Ah, xlo, acc[mi], 0, 0, 0);
            acc[mi] = __builtin_amdgcn_mfma_f32_16x16x32_bf16(Al, xhi, acc[mi], 0, 0, 0);
            acc[mi] = __builtin_amdgcn_mfma_f32_16x16x32_bf16(Ah, xhi, acc[mi], 0, 0, 0);
        }
    }
#pragma unroll
    for (int mi = 0; mi < 4; ++mi) {
#pragma unroll
        for (int r = 0; r < 4; ++r) {
            int e = mi * 16 + lk * 4 + r;
            eb[px * 66 + e] = f2bf(acc[mi][r]);
        }
    }
    __syncthreads();
    unsigned short* dst = Vvb + (size_t)blk * 4096;
#pragma unroll
    for (int i = 0; i < 2; ++i) {
        int flat16 = i * 256 + t;            // 0..511
        int f3 = flat16 >> 6;
        int h = (flat16 >> 3) & 7;
        int px8 = (flat16 & 7) * 8;
        u16x8 vv;
#pragma unroll
        for (int u = 0; u < 8; ++u) vv[u] = eb[(px8 + u) * 66 + f3 * 8 + h];
        *(u16x8*)&dst[flat16 * 8] = vv;
    }
    Vavg[(size_t)blk * DVC + t] =
        (avgw[t] + avgw[256 + t] + avgw[512 + t] + avgw[768 + t]) * 0.015625f;
}

// ---------------------------------------------------------------------------
// K3b: pack Vvb [b][N][f3][h][px] -> Vp fragment order (unchanged)
__global__ __launch_bounds__(256) void k3b_pack(
    const unsigned short* __restrict__ Vvb, unsigned short* __restrict__ Vp) {
    __shared__ unsigned short tile[32 * 576];   // [N][f3][72]
    int kt = blockIdx.x, bh = blockIdx.y;
    int b = bh >> 3, h = bh & 7;
    int t = threadIdx.x;
#pragma unroll
    for (int it = 0; it < 8; ++it) {
        int flat = it * 256 + t;                // 0..2047
        int r5 = flat >> 6;
        int c = flat & 63;
        int f3 = c >> 3, px8 = (c & 7) * 8;
        const unsigned short* s =
            Vvb + ((size_t)(b * NTOT + kt * 32 + r5) * 8 + f3) * 512 + h * 64 + px8;
        *(u16x8*)&tile[r5 * 576 + f3 * 72 + px8] = *(const u16x8*)s;
    }
    __syncthreads();
    unsigned short* dst = Vp + ((size_t)bh * 49 + kt) * 16384;
#pragma unroll
    for (int it = 0; it < 8; ++it) {
        int flato = it * 256 + t;
        int lane = flato & 63;
        int kh = (flato >> 6) & 1;
        int sub = (flato >> 7) & 3;
        int w = flato >> 9;
        int l31 = lane & 31, hh = lane >> 5;
        int f = w * 128 + sub * 32 + l31;
        int kbase = kh * 16 + hh * 8;
        u16x8 v;
#pragma unroll
        for (int j = 0; j < 8; ++j)
            v[j] = tile[(kbase + j) * 576 + (f & 7) * 72 + (f >> 3)];
        *(u16x8*)&dst[(size_t)flato * 8] = v;
    }
}

// ---------------------------------------------------------------------------
// K4: flash attention — R14 champion structure + R15: QK accumulation split
// into two independent 3-MFMA chains (halved dep-latency), s_setprio around
// MFMA clusters (waves are barrier-free/phase-diverse -> scheduler lever).
__global__ __launch_bounds__(256) void k4_attn(
    const unsigned short* __restrict__ Qp, const unsigned short* __restrict__ Kp,
    const unsigned short* __restrict__ Vp, float* __restrict__ rw) {
    __shared__ float ebuf[32 * 132];
    int wg = blockIdx.x;
    int qt = wg >> 4, bh = wg & 15;       // wg%8 == bh%8 -> XCD affinity
    int q0 = qt * 32;
    int t = threadIdx.x;
    int w = t >> 6, lane = t & 63;
    int l31 = lane & 31, hh = lane >> 5;

    const unsigned short* __restrict__ Qpb = Qp + ((size_t)(bh * 49 + qt) * 4) * 512 + lane * 8;
    const unsigned short* __restrict__ Kpb = Kp + (size_t)bh * 49 * 2048 + lane * 8;
    const unsigned short* __restrict__ Vpb = Vp + (size_t)bh * 49 * 16384 + lane * 8;

    s16x8 qa0 = *(const s16x8*)&Qpb[0];
    s16x8 qa1 = *(const s16x8*)&Qpb[512];
    s16x8 ql0 = *(const s16x8*)&Qpb[1024];
    s16x8 ql1 = *(const s16x8*)&Qpb[1536];

    // K fragments for tile 0 (cross-tile prefetch registers)
    s16x8 ka0 = *(const s16x8*)&Kpb[0];
    s16x8 ka1 = *(const s16x8*)&Kpb[512];
    s16x8 kl0 = *(const s16x8*)&Kpb[1024];
    s16x8 kl1 = *(const s16x8*)&Kpb[1536];

    float m = -1e30f, lsum = 0.f;
    f32x16 acc[4];
#pragma unroll
    for (int s = 0; s < 4; ++s) acc[s] = (f32x16)0.f;

    for (int kt = 0; kt < NTOT / 32; ++kt) {
        // ---- V fragment loads (consumed last) ----
        const unsigned short* Vtile = Vpb + (size_t)kt * 16384 + (w * 8) * 512;
        s16x8 va[8];
#pragma unroll
        for (int fr = 0; fr < 8; ++fr)
            va[fr] = *(const s16x8*)&Vtile[fr * 512];
        // ---- prefetch next K tile ----
        int ktn = (kt < 48) ? kt + 1 : 48;
        const unsigned short* Ktn = Kpb + (size_t)ktn * 2048;
        s16x8 kn0 = *(const s16x8*)&Ktn[0];
        s16x8 kn1 = *(const s16x8*)&Ktn[512];
        s16x8 kn2 = *(const s16x8*)&Ktn[1024];
        s16x8 kn3 = *(const s16x8*)&Ktn[1536];

        // ---- S^T = K @ Q^T: two independent 3-MFMA chains, then merge ----
        __builtin_amdgcn_s_setprio(1);
        f32x16 sacc0 = (f32x16)0.f;
        f32x16 sacc1 = (f32x16)0.f;
        sacc0 = __builtin_amdgcn_mfma_f32_32x32x16_bf16(kl0, qa0, sacc0, 0, 0, 0);
        sacc1 = __builtin_amdgcn_mfma_f32_32x32x16_bf16(kl1, qa1, sacc1, 0, 0, 0);
        sacc0 = __builtin_amdgcn_mfma_f32_32x32x16_bf16(ka0, ql0, sacc0, 0, 0, 0);
        sacc1 = __builtin_amdgcn_mfma_f32_32x32x16_bf16(ka1, ql1, sacc1, 0, 0, 0);
        sacc0 = __builtin_amdgcn_mfma_f32_32x32x16_bf16(ka0, qa0, sacc0, 0, 0, 0);
        sacc1 = __builtin_amdgcn_mfma_f32_32x32x16_bf16(ka1, qa1, sacc1, 0, 0, 0);
        __builtin_amdgcn_s_setprio(0);
        f32x16 sacc = sacc0 + sacc1;

        // ---- online softmax stats (log2 domain), max3-fused tree ----
        float t0 = fmaxf(fmaxf(sacc[0], sacc[1]), sacc[2]);
        float t1 = fmaxf(fmaxf(sacc[3], sacc[4]), sacc[5]);
        float t2 = fmaxf(fmaxf(sacc[6], sacc[7]), sacc[8]);
        float t3 = fmaxf(fmaxf(sacc[9], sacc[10]), sacc[11]);
        float t4 = fmaxf(fmaxf(sacc[12], sacc[13]), sacc[14]);
        float u0 = fmaxf(fmaxf(t0, t1), t2);
        float u1 = fmaxf(t3, t4);
        float tmax = fmaxf(fmaxf(u0, u1), sacc[15]);
        tmax = fmaxf(tmax, __shfl_xor(tmax, 32, 64));
        if (__any(tmax > m + 11.5f)) {        // defer-max, log2 units (~e^8)
            float mn = fmaxf(m, tmax);
            float sc = fexp2(m - mn);
#pragma unroll
            for (int s = 0; s < 4; ++s) acc[s] = acc[s] * sc;
            lsum *= sc;
            m = mn;
        }
        // ---- P = 2^(S - m) (single v_exp each), pack bf16 pairs ----
        unsigned P2[8];
        float ts0 = 0.f, ts1 = 0.f;
#pragma unroll
        for (int j = 0; j < 8; ++j) {
            float pa = fexp2(sacc[2 * j] - m);
            float pb = fexp2(sacc[2 * j + 1] - m);
            ts0 += pa; ts1 += pb;
            P2[j] = cvt_pk_bf16(pa, pb);
        }
        float tsum = ts0 + ts1;
        lsum += tsum + __shfl_xor(tsum, 32, 64);
        // ---- half-exchange via permlane32_swap ----
        permlane32_swap(P2[0], P2[2]);
        permlane32_swap(P2[1], P2[3]);
        permlane32_swap(P2[4], P2[6]);
        permlane32_swap(P2[5], P2[7]);
        u32x4 b0u, b1u;
        b0u[0] = P2[0]; b0u[1] = P2[1]; b0u[2] = P2[2]; b0u[3] = P2[3];
        b1u[0] = P2[4]; b1u[1] = P2[5]; b1u[2] = P2[6]; b1u[3] = P2[7];
        s16x8 pb0 = __builtin_bit_cast(s16x8, b0u);
        s16x8 pb1 = __builtin_bit_cast(s16x8, b1u);

        // ---- PV: O^T[f][q] += V^T[f][k] P^T[k][q] ----
        __builtin_amdgcn_s_setprio(1);
#pragma unroll
        for (int sub = 0; sub < 4; ++sub) {
            acc[sub] = __builtin_amdgcn_mfma_f32_32x32x16_bf16(va[2 * sub],     pb0, acc[sub], 0, 0, 0);
            acc[sub] = __builtin_amdgcn_mfma_f32_32x32x16_bf16(va[2 * sub + 1], pb1, acc[sub], 0, 0, 0);
        }
        __builtin_amdgcn_s_setprio(0);
        ka0 = kn0; ka1 = kn1; kl0 = kn2; kl1 = kn3;
    }

    // ---- epilogue: normalize, chunked LDS transpose, coalesced store ----
    float inv = 1.f / lsum;
    float* rwg = rw + ((size_t)bh * NTOT + q0) * FDIM;
#pragma unroll
    for (int c = 0; c < 4; ++c) {
        __syncthreads();
        if (w == c) {
#pragma unroll
            for (int sub = 0; sub < 4; ++sub) {
#pragma unroll
                for (int r = 0; r < 16; ++r) {
                    int fl = sub * 32 + (r & 3) + 8 * (r >> 2) + 4 * hh;
                    ebuf[l31 * 132 + fl] = acc[sub][r] * inv;
                }
            }
        }
        __syncthreads();
        int qr = t >> 3, cb = (t & 7) * 16;
#pragma unroll
        for (int j = 0; j < 4; ++j) {
            *(float4*)&rwg[(size_t)qr * FDIM + c * 128 + cb + j * 4] =
                *(const float4*)&ebuf[qr * 132 + cb + j * 4];
        }
    }
}

// ---------------------------------------------------------------------------
// K5: MFMA GEMM per window: out(64n x 256c) = rwL(64n x 64j) @ Wback(64j x 256c)
__global__ __launch_bounds__(256) void k5_back(
    const float* __restrict__ rw, const unsigned short* __restrict__ Wp,
    float* __restrict__ out) {
    __shared__ unsigned short SB[2 * 64 * 72];   // hi plane, lo plane (18.4 KB)
    unsigned short* BhL = SB;
    unsigned short* BlL = SB + 64 * 72;
    int blk = blockIdx.x;
    int b = blk / NTOT, N = blk % NTOT;
    int src = N / NSRC, nloc = N % NSRC;
    int wh = nloc / 28, ww = nloc % 28;
    int t = threadIdx.x;
    int w = t >> 6, lane = t & 63;
    int lm = lane & 15, lk = lane >> 4;
    int pbase = (b * 224 + wh * 8) * 224 + ww * 8;

#pragma unroll
    for (int i = 0; i < 4; ++i) {
        int flat4 = i * 256 + t;
        int h = flat4 >> 7;
        int f0 = (flat4 & 127) * 4;
        float4 v = *(const float4*)&rw[((size_t)(b * NHD + h) * NTOT + N) * FDIM + f0];
        int n = f0 >> 3;
        int ebase = f0 & 7;
        float vv[4] = {v.x, v.y, v.z, v.w};
#pragma unroll
        for (int u = 0; u < 4; ++u) {
            int j8 = ebase + u;
            unsigned short h16, l16;
            split_bf(vv[u], h16, l16);
            int col = ((j8 ^ (n & 7)) << 3) | h;
            BhL[n * 72 + col] = h16;
            BlL[n * 72 + col] = l16;
        }
    }
    __syncthreads();

    f32x4 acc[4][4];
#pragma unroll
    for (int mi = 0; mi < 4; ++mi)
#pragma unroll
        for (int nt = 0; nt < 4; ++nt) acc[mi][nt] = (f32x4)0.f;

    const unsigned short* Wpw = Wp + (size_t)(w * 4) * 2048 + lane * 8;
#pragma unroll
    for (int kc = 0; kc < 2; ++kc) {
        s16x8 Ah[4], Al[4], Bh4[4], Bl4[4];
#pragma unroll
        for (int mi = 0; mi < 4; ++mi) {
            int base = mi * 2048 + kc * 1024;
            Ah[mi] = *(const s16x8*)&Wpw[base];
            Al[mi] = *(const s16x8*)&Wpw[base + 512];
        }
#pragma unroll
        for (int nt = 0; nt < 4; ++nt) {
            int n = nt * 16 + lm;
            int addr = n * 72 + (((kc * 4 + lk) ^ (n & 7)) << 3);
            Bh4[nt] = *(const s16x8*)&BhL[addr];
            Bl4[nt] = *(const s16x8*)&BlL[addr];
        }
#pragma unroll
        for (int mi = 0; mi < 4; ++mi)
#pragma unroll
            for (int nt = 0; nt < 4; ++nt) {
                acc[mi][nt] = __builtin_amdgcn_mfma_f32_16x16x32_bf16(Ah[mi], Bl4[nt], acc[mi][nt], 0, 0, 0);
                acc[mi][nt] = __builtin_amdgcn_mfma_f32_16x16x32_bf16(Al[mi], Bh4[nt], acc[mi][nt], 0, 0, 0);
                acc[mi][nt] = __builtin_amdgcn_mfma_f32_16x16x32_bf16(Ah[mi], Bh4[nt], acc[mi][nt], 0, 0, 0);
            }
    }

    float* eb = (float*)SB;
    float* outp = out + (size_t)src * OUT_PER_SRC;
#pragma unroll
    for (int ch = 0; ch < 4; ++ch) {
        __syncthreads();
        if (w == ch) {
#pragma unroll
            for (int mi = 0; mi < 4; ++mi)
#pragma unroll
                for (int nt = 0; nt < 4; ++nt)
#pragma unroll
                    for (int r = 0; r < 4; ++r) {
                        int n = nt * 16 + lm;
                        int cl = mi * 16 + lk * 4 + r;
                        eb[n * 68 + cl] = acc[mi][nt][r];
                    }
        }
        __syncthreads();
#pragma unroll
        for (int i = 0; i < 4; ++i) {
            int fl4 = i * 256 + t;
            int n = fl4 >> 4, c4 = (fl4 & 15) * 4;
            int opix = pbase + (n >> 3) * 224 + (n & 7);
            *(float4*)&outp[(size_t)opix * DVC + ch * 64 + c4] =
                *(const float4*)&eb[n * 68 + c4];
        }
    }
}

// ---------------------------------------------------------------------------
extern "C" void kernel_launch(void* const* d_in, const int* in_sizes, int n_in,
                              void* d_out, int out_size, void* d_ws, size_t ws_size,
                              hipStream_t stream) {
    const float* v0   = (const float*)d_in[0];
    const float* c0   = (const float*)d_in[1];
    const float* v1   = (const float*)d_in[2];
    const float* c1   = (const float*)d_in[3];
    const float* Wqkv = (const float*)d_in[4];
    const float* bqkv = (const float*)d_in[5];
    const float* gv   = (const float*)d_in[6];
    const float* Wqkc = (const float*)d_in[7];
    const float* bqkc = (const float*)d_in[8];
    const float* gc   = (const float*)d_in[9];
    const float* Wv   = (const float*)d_in[10];
    const float* Wbk  = (const float*)d_in[11];

    float* ws = (float*)d_ws;
    float* rw   = ws;                        // 12,845,056 fl (aliases Vavg/Cavg)
    float* Vavg = ws;                        //    802,816 fl
    float* Cavg = ws + 802816;               //    200,704 fl
    unsigned short* Qp   = (unsigned short*)(ws + 12845056);  // 1,605,632 u16
    unsigned short* Kp   = (unsigned short*)(ws + 13647872);  // 1,605,632 u16
    unsigned short* Wvp  = (unsigned short*)(ws + 14450688);  //    32,768 u16
    unsigned short* Vvb  = (unsigned short*)(ws + 14467072);  // 12,845,056 u16
    unsigned short* Vp   = (unsigned short*)(ws + 20889600);  // 12,845,056 u16
    unsigned short* Wp   = (unsigned short*)(ws + 27312128);  //    65,536 u16
    // total ends at 27,344,896 fl = 109.4 MB

    float* outp = (float*)d_out;

    kz_zero   <<<1568, 256, 0, stream>>>(Qp);   // zeros Qp+Kp (contiguous)
    k0c_wvpack<<<256, 256, 0, stream>>>(Wv, Wvp);
    k0b_wback <<<256, 256, 0, stream>>>(Wbk, Wp);
    k3_vv     <<<2 * NTOT, 256, 0, stream>>>(v0, v1, Wvp, Vvb, Vavg);
    k1c_avg   <<<784, 256, 0, stream>>>(c0, c1, Cavg);
    k2_qk     <<<2 * NTOT, 256, 0, stream>>>(Vavg, Cavg, Wqkv, bqkv, gv, Wqkc, bqkc, gc, Qp, Kp);
    k3b_pack  <<<dim3(49, 16), 256, 0, stream>>>(Vvb, Vp);
    k4_attn   <<<784, 256, 0, stream>>>(Qp, Kp, Vp, rw);
    k5_back   <<<2 * NTOT, 256, 0, stream>>>(rw, Wp, outp);
}

// Round 16
// 340.600 us; speedup vs baseline: 1.0594x; 1.0594x over previous
//
#include <hip/hip_runtime.h>

#define NSRC 784
#define NTOT 1568
#define NHD 8
#define DVC 256
#define DCC 64
#define D20 20
#define FDIM 512
#define OUT_PER_SRC 25690112

typedef short s16x8 __attribute__((ext_vector_type(8)));
typedef unsigned short u16x8 __attribute__((ext_vector_type(8)));
typedef unsigned short u16x4 __attribute__((ext_vector_type(4)));
typedef float f32x4 __attribute__((ext_vector_type(4)));
typedef float f32x16 __attribute__((ext_vector_type(16)));
typedef unsigned u32x4 __attribute__((ext_vector_type(4)));

#define LOG2E 1.4426950408889634f

__device__ __forceinline__ unsigned short f2bf(float x) {
    unsigned u = __float_as_uint(x);
    unsigned r = (u + 0x7FFFu + ((u >> 16) & 1u)) >> 16;   // RNE
    return (unsigned short)r;
}

__device__ __forceinline__ unsigned cvt_pk_bf16(float lo, float hi) {
    unsigned r;
    asm volatile("v_cvt_pk_bf16_f32 %0, %1, %2" : "=v"(r) : "v"(lo), "v"(hi));
    return r;
}

// native 2^x (single v_exp_f32, no libcall guards, no pre-multiply)
__device__ __forceinline__ float fexp2(float x) {
    float r;
    asm("v_exp_f32 %0, %1" : "=v"(r) : "v"(x));
    return r;
}

// split float into bf16 hi + bf16 lo correction (x ~= hi + lo)
__device__ __forceinline__ void split_bf(float x, unsigned short& hi, unsigned short& lo) {
    unsigned short h = f2bf(x);
    float hf = __uint_as_float(((unsigned)h) << 16);
    hi = h;
    lo = f2bf(x - hf);
}

// v_permlane32_swap_b32: a' = [a.lo32 | b.lo32], b' = [a.hi32 | b.hi32]
__device__ __forceinline__ void permlane32_swap(unsigned& a, unsigned& b) {
    asm volatile("v_permlane32_swap_b32 %0, %1" : "+v"(a), "+v"(b));
}

// ---------------------------------------------------------------------------
// KZ: zero Qp+Kp (contiguous) — clears the d in [20,32) pad slots
__global__ __launch_bounds__(256) void kz_zero(unsigned short* __restrict__ p) {
    size_t i = (size_t)blockIdx.x * 256 + threadIdx.x;
    u16x8 z = (u16x8)0;
    *(u16x8*)&p[i * 8] = z;
}

// ---------------------------------------------------------------------------
// K0c: pack Wv(256dd x 64e) -> A-fragment order hi/lo for k3
__global__ __launch_bounds__(256) void k0c_wvpack(
    const float* __restrict__ Wv, unsigned short* __restrict__ Wvp) {
    int idx = blockIdx.x * 256 + threadIdx.x;        // 0..65535
    int j = idx & 7, lane = (idx >> 3) & 63, hl = (idx >> 9) & 1;
    int c = (idx >> 10) & 7, mi = idx >> 13;
    int e = mi * 16 + (lane & 15);
    int dd = c * 32 + (lane >> 4) * 8 + j;
    unsigned short h, l;
    split_bf(Wv[dd * DCC + e], h, l);
    Wvp[idx] = hl ? l : h;
}

// ---------------------------------------------------------------------------
// K0b: pack Wback(64j x 256c) -> A-fragment order hi/lo
__global__ __launch_bounds__(256) void k0b_wback(
    const float* __restrict__ Wb, unsigned short* __restrict__ Wp) {
    int idx = blockIdx.x * 256 + threadIdx.x;        // 0..65535
    int jj = idx & 7, lane = (idx >> 3) & 63, hl = (idx >> 9) & 1;
    int kc = (idx >> 10) & 1, mt = idx >> 11;
    int c = mt * 16 + (lane & 15);
    int j = kc * 32 + (lane >> 4) * 8 + jj;
    unsigned short h, l;
    split_bf(Wb[j * 256 + c], h, l);
    Wp[idx] = hl ? l : h;
}

// ---------------------------------------------------------------------------
// K1c: window average of coords only
__global__ __launch_bounds__(256) void k1c_avg(
    const float* __restrict__ c0, const float* __restrict__ c1,
    float* __restrict__ Cavg) {
    int wi = blockIdx.x * 4 + (threadIdx.x >> 6);
    int d = threadIdx.x & 63;
    int b = wi / NTOT, N = wi % NTOT;
    int src = N / NSRC, nloc = N % NSRC;
    int wh = nloc / 28, ww = nloc % 28;
    const float* __restrict__ C = src ? c1 : c0;
    int pbase = (b * 224 + wh * 8) * 224 + ww * 8;
    float s = 0.f;
#pragma unroll 8
    for (int p = 0; p < 64; ++p)
        s += C[(size_t)(pbase + (p >> 3) * 224 + (p & 7)) * DCC + d];
    Cavg[(size_t)wi * DCC + d] = s * 0.015625f;
}

// ---------------------------------------------------------------------------
// K2: qk = rmsnorm(avg @ Wqk + b, g); writes Q/K bf16 hi/lo fragments in
// k4's packed lane order. Q pre-scaled by log2(e)/sqrt(I) -> exp2 softmax.
__global__ __launch_bounds__(256) void k2_qk(
    const float* __restrict__ Vavg, const float* __restrict__ Cavg,
    const float* __restrict__ Wqkv, const float* __restrict__ bqkv, const float* __restrict__ gv,
    const float* __restrict__ Wqkc, const float* __restrict__ bqkc, const float* __restrict__ gc,
    unsigned short* __restrict__ Qp, unsigned short* __restrict__ Kp) {
    __shared__ float xv[DVC];
    __shared__ float xc[DCC];
    __shared__ float wred[4];
    int blk = blockIdx.x;
    int b = blk / NTOT, N = blk % NTOT;
    int t = threadIdx.x;
    int tile = N >> 5, l31 = N & 31;
    xv[t] = Vavg[(size_t)blk * DVC + t];
    if (t < DCC) xc[t] = Cavg[(size_t)blk * DCC + t];
    __syncthreads();
    float yv = bqkv[t];
#pragma unroll 4
    for (int d = 0; d < DVC; ++d) yv += xv[d] * Wqkv[d * 256 + t];
    float ss = yv * yv;
#pragma unroll
    for (int off = 32; off; off >>= 1) ss += __shfl_xor(ss, off, 64);
    if ((t & 63) == 0) wred[t >> 6] = ss;
    __syncthreads();
    float tot = wred[0] + wred[1] + wred[2] + wred[3];
    float rv = rsqrtf(tot * (1.f / 256.f) + 1e-6f);
    float yn = yv * rv * gv[t];
    int h = t >> 5, c = t & 31;
    int bh = b * NHD + h;
    {
        int isq = (c < 16);
        int d = isq ? c : c - 16;
        float val = isq ? yn * (0.088388347648318447f * LOG2E) : yn;
        unsigned short h16, l16;
        split_bf(val, h16, l16);
        int hh = d >> 3, j = d & 7;
        size_t base = ((size_t)(bh * 49 + tile) * 4) * 512 + (size_t)(hh * 32 + l31) * 8 + j;
        unsigned short* dst = isq ? Qp : Kp;
        dst[base] = h16;
        dst[base + 1024] = l16;
    }
    if (t < DCC) {
        float yc = bqkc[t];
#pragma unroll 4
        for (int d = 0; d < DCC; ++d) yc += xc[d] * Wqkc[d * 64 + t];
        float sc = yc * yc;
#pragma unroll
        for (int off = 32; off; off >>= 1) sc += __shfl_xor(sc, off, 64);
        float rc = rsqrtf(sc * (1.f / 64.f) + 1e-6f);
        float ycn = yc * rc * gc[t];
        int h2 = t >> 3, c2 = t & 7;
        int bh2 = b * NHD + h2;
        int isq = (c2 < 4);
        int dd = isq ? c2 : c2 - 4;
        float val = isq ? ycn * (0.17677669529663687f * LOG2E) : ycn;
        unsigned short h16, l16;
        split_bf(val, h16, l16);
        size_t base = ((size_t)(bh2 * 49 + tile) * 4 + 1) * 512 + (size_t)l31 * 8 + dd;
        unsigned short* dst = isq ? Qp : Kp;
        dst[base] = h16;
        dst[base + 1024] = l16;
    }
}

// ---------------------------------------------------------------------------
// K3: per-window GEMM as D[e][px] = W^T @ X^T — zero-LDS, zero-barrier main
// loop. (unchanged from R10)
__global__ __launch_bounds__(256) void k3_vv(
    const float* __restrict__ v0, const float* __restrict__ v1,
    const unsigned short* __restrict__ Wvp,
    unsigned short* __restrict__ Vvb, float* __restrict__ Vavg) {
    __shared__ unsigned short eb[64 * 66];   // 8.4 KB
    __shared__ float avgw[1024];             // 4 KB
    int blk = blockIdx.x;
    int b = blk / NTOT, N = blk % NTOT;
    int src = N / NSRC, nloc = N % NSRC;
    int wh = nloc / 28, ww = nloc % 28;
    const float* __restrict__ V = src ? v1 : v0;
    int t = threadIdx.x;
    int w = t >> 6, lane = t & 63;
    int lm = lane & 15, lk = lane >> 4;
    int px = w * 16 + lm;
    int pbase = (b * 224 + wh * 8) * 224 + ww * 8;
    const float* __restrict__ xrow =
        V + (size_t)(pbase + (px >> 3) * 224 + (px & 7)) * DVC + lk * 8;

    f32x4 acc[4];
#pragma unroll
    for (int mi = 0; mi < 4; ++mi) acc[mi] = (f32x4)0.f;

#pragma unroll
    for (int c = 0; c < 8; ++c) {
        float4 x0 = *(const float4*)&xrow[c * 32];
        float4 x1 = *(const float4*)&xrow[c * 32 + 4];
        float xv8[8] = {x0.x, x0.y, x0.z, x0.w, x1.x, x1.y, x1.z, x1.w};
        u16x8 bhu, blu;
#pragma unroll
        for (int j = 0; j < 8; ++j) {
            unsigned short hq, lq;
            split_bf(xv8[j], hq, lq);
            bhu[j] = hq; blu[j] = lq;
        }
        s16x8 xhi = __builtin_bit_cast(s16x8, bhu);
        s16x8 xlo = __builtin_bit_cast(s16x8, blu);
        float sv[8] = {xv8[0], xv8[1], xv8[2], xv8[3], xv8[4], xv8[5], xv8[6], xv8[7]};
#pragma unroll
        for (int off = 1; off <= 8; off <<= 1)
#pragma unroll
            for (int j = 0; j < 8; ++j) sv[j] += __shfl_xor(sv[j], off, 64);
        if (lm == 0) {
#pragma unroll
            for (int j = 0; j < 8; ++j)
                avgw[w * 256 + c * 32 + lk * 8 + j] = sv[j];
        }
#pragma unroll
        for (int mi = 0; mi < 4; ++mi) {
            const unsigned short* Wf = Wvp + (size_t)((mi * 8 + c) * 2) * 512 + lane * 8;
            s16x8 Ah = *(const s16x8*)&Wf[0];
            s16x8 Al = *(const s16x8*)&Wf[512];
            acc[mi] = __builtin_amdgcn_mfma_f32_16x16x32_bf16(Ah, xlo, acc[mi], 0, 0, 0);
            acc[mi] = __builtin_amdgcn_mfma_f32_16x16x32_bf16(Al, xhi, acc[mi], 0, 0, 0);
            acc[mi] = __builtin_amdgcn_mfma_f32_16x16x32_bf16(Ah, xhi, acc[mi], 0, 0, 0);
        }
    }
#pragma unroll
    for (int mi = 0; mi < 4; ++mi) {
#pragma unroll
        for (int r = 0; r < 4; ++r) {
            int e = mi * 16 + lk * 4 + r;
            eb[px * 66 + e] = f2bf(acc[mi][r]);
        }
    }
    __syncthreads();
    unsigned short* dst = Vvb + (size_t)blk * 4096;
#pragma unroll
    for (int i = 0; i < 2; ++i) {
        int flat16 = i * 256 + t;            // 0..511
        int f3 = flat16 >> 6;
        int h = (flat16 >> 3) & 7;
        int px8 = (flat16 & 7) * 8;
        u16x8 vv;
#pragma unroll
        for (int u = 0; u < 8; ++u) vv[u] = eb[(px8 + u) * 66 + f3 * 8 + h];
        *(u16x8*)&dst[flat16 * 8] = vv;
    }
    Vavg[(size_t)blk * DVC + t] =
        (avgw[t] + avgw[256 + t] + avgw[512 + t] + avgw[768 + t]) * 0.015625f;
}

// ---------------------------------------------------------------------------
// K3b: pack Vvb [b][N][f3][h][px] -> Vp fragment order (unchanged)
__global__ __launch_bounds__(256) void k3b_pack(
    const unsigned short* __restrict__ Vvb, unsigned short* __restrict__ Vp) {
    __shared__ unsigned short tile[32 * 576];   // [N][f3][72]
    int kt = blockIdx.x, bh = blockIdx.y;
    int b = bh >> 3, h = bh & 7;
    int t = threadIdx.x;
#pragma unroll
    for (int it = 0; it < 8; ++it) {
        int flat = it * 256 + t;                // 0..2047
        int r5 = flat >> 6;
        int c = flat & 63;
        int f3 = c >> 3, px8 = (c & 7) * 8;
        const unsigned short* s =
            Vvb + ((size_t)(b * NTOT + kt * 32 + r5) * 8 + f3) * 512 + h * 64 + px8;
        *(u16x8*)&tile[r5 * 576 + f3 * 72 + px8] = *(const u16x8*)s;
    }
    __syncthreads();
    unsigned short* dst = Vp + ((size_t)bh * 49 + kt) * 16384;
#pragma unroll
    for (int it = 0; it < 8; ++it) {
        int flato = it * 256 + t;
        int lane = flato & 63;
        int kh = (flato >> 6) & 1;
        int sub = (flato >> 7) & 3;
        int w = flato >> 9;
        int l31 = lane & 31, hh = lane >> 5;
        int f = w * 128 + sub * 32 + l31;
        int kbase = kh * 16 + hh * 8;
        u16x8 v;
#pragma unroll
        for (int j = 0; j < 8; ++j)
            v[j] = tile[(kbase + j) * 576 + (f & 7) * 72 + (f >> 3)];
        *(u16x8*)&dst[(size_t)flato * 8] = v;
    }
}

// ---------------------------------------------------------------------------
// K4: flash attention — exact R14 champion structure (single sacc chain,
// VGPR-neutral) + s_setprio only (zero register cost).
__global__ __launch_bounds__(256) void k4_attn(
    const unsigned short* __restrict__ Qp, const unsigned short* __restrict__ Kp,
    const unsigned short* __restrict__ Vp, float* __restrict__ rw) {
    __shared__ float ebuf[32 * 132];
    int wg = blockIdx.x;
    int qt = wg >> 4, bh = wg & 15;       // wg%8 == bh%8 -> XCD affinity
    int q0 = qt * 32;
    int t = threadIdx.x;
    int w = t >> 6, lane = t & 63;
    int l31 = lane & 31, hh = lane >> 5;

    const unsigned short* __restrict__ Qpb = Qp + ((size_t)(bh * 49 + qt) * 4) * 512 + lane * 8;
    const unsigned short* __restrict__ Kpb = Kp + (size_t)bh * 49 * 2048 + lane * 8;
    const unsigned short* __restrict__ Vpb = Vp + (size_t)bh * 49 * 16384 + lane * 8;

    s16x8 qa0 = *(const s16x8*)&Qpb[0];
    s16x8 qa1 = *(const s16x8*)&Qpb[512];
    s16x8 ql0 = *(const s16x8*)&Qpb[1024];
    s16x8 ql1 = *(const s16x8*)&Qpb[1536];

    // K fragments for tile 0 (cross-tile prefetch registers)
    s16x8 ka0 = *(const s16x8*)&Kpb[0];
    s16x8 ka1 = *(const s16x8*)&Kpb[512];
    s16x8 kl0 = *(const s16x8*)&Kpb[1024];
    s16x8 kl1 = *(const s16x8*)&Kpb[1536];

    float m = -1e30f, lsum = 0.f;
    f32x16 acc[4];
#pragma unroll
    for (int s = 0; s < 4; ++s) acc[s] = (f32x16)0.f;

    for (int kt = 0; kt < NTOT / 32; ++kt) {
        // ---- V fragment loads (consumed last) ----
        const unsigned short* Vtile = Vpb + (size_t)kt * 16384 + (w * 8) * 512;
        s16x8 va[8];
#pragma unroll
        for (int fr = 0; fr < 8; ++fr)
            va[fr] = *(const s16x8*)&Vtile[fr * 512];
        // ---- prefetch next K tile ----
        int ktn = (kt < 48) ? kt + 1 : 48;
        const unsigned short* Ktn = Kpb + (size_t)ktn * 2048;
        s16x8 kn0 = *(const s16x8*)&Ktn[0];
        s16x8 kn1 = *(const s16x8*)&Ktn[512];
        s16x8 kn2 = *(const s16x8*)&Ktn[1024];
        s16x8 kn3 = *(const s16x8*)&Ktn[1536];

        // ---- S^T = K @ Q^T (32k x 32q), 3-term hi/lo, exp2 domain ----
        __builtin_amdgcn_s_setprio(1);
        f32x16 sacc = (f32x16)0.f;
        sacc = __builtin_amdgcn_mfma_f32_32x32x16_bf16(kl0, qa0, sacc, 0, 0, 0);
        sacc = __builtin_amdgcn_mfma_f32_32x32x16_bf16(ka0, ql0, sacc, 0, 0, 0);
        sacc = __builtin_amdgcn_mfma_f32_32x32x16_bf16(ka0, qa0, sacc, 0, 0, 0);
        sacc = __builtin_amdgcn_mfma_f32_32x32x16_bf16(kl1, qa1, sacc, 0, 0, 0);
        sacc = __builtin_amdgcn_mfma_f32_32x32x16_bf16(ka1, ql1, sacc, 0, 0, 0);
        sacc = __builtin_amdgcn_mfma_f32_32x32x16_bf16(ka1, qa1, sacc, 0, 0, 0);
        __builtin_amdgcn_s_setprio(0);

        // ---- online softmax stats (log2 domain), max3-fused tree ----
        float t0 = fmaxf(fmaxf(sacc[0], sacc[1]), sacc[2]);
        float t1 = fmaxf(fmaxf(sacc[3], sacc[4]), sacc[5]);
        float t2 = fmaxf(fmaxf(sacc[6], sacc[7]), sacc[8]);
        float t3 = fmaxf(fmaxf(sacc[9], sacc[10]), sacc[11]);
        float t4 = fmaxf(fmaxf(sacc[12], sacc[13]), sacc[14]);
        float u0 = fmaxf(fmaxf(t0, t1), t2);
        float u1 = fmaxf(t3, t4);
        float tmax = fmaxf(fmaxf(u0, u1), sacc[15]);
        tmax = fmaxf(tmax, __shfl_xor(tmax, 32, 64));
        if (__any(tmax > m + 11.5f)) {        // defer-max, log2 units (~e^8)
            float mn = fmaxf(m, tmax);
            float sc = fexp2(m - mn);
#pragma unroll
            for (int s = 0; s < 4; ++s) acc[s] = acc[s] * sc;
            lsum *= sc;
            m = mn;
        }
        // ---- P = 2^(S - m) (single v_exp each), pack bf16 pairs ----
        unsigned P2[8];
        float ts0 = 0.f, ts1 = 0.f;
#pragma unroll
        for (int j = 0; j < 8; ++j) {
            float pa = fexp2(sacc[2 * j] - m);
            float pb = fexp2(sacc[2 * j + 1] - m);
            ts0 += pa; ts1 += pb;
            P2[j] = cvt_pk_bf16(pa, pb);
        }
        float tsum = ts0 + ts1;
        lsum += tsum + __shfl_xor(tsum, 32, 64);
        // ---- half-exchange via permlane32_swap ----
        permlane32_swap(P2[0], P2[2]);
        permlane32_swap(P2[1], P2[3]);
        permlane32_swap(P2[4], P2[6]);
        permlane32_swap(P2[5], P2[7]);
        u32x4 b0u, b1u;
        b0u[0] = P2[0]; b0u[1] = P2[1]; b0u[2] = P2[2]; b0u[3] = P2[3];
        b1u[0] = P2[4]; b1u[1] = P2[5]; b1u[2] = P2[6]; b1u[3] = P2[7];
        s16x8 pb0 = __builtin_bit_cast(s16x8, b0u);
        s16x8 pb1 = __builtin_bit_cast(s16x8, b1u);

        // ---- PV: O^T[f][q] += V^T[f][k] P^T[k][q] ----
        __builtin_amdgcn_s_setprio(1);
#pragma unroll
        for (int sub = 0; sub < 4; ++sub) {
            acc[sub] = __builtin_amdgcn_mfma_f32_32x32x16_bf16(va[2 * sub],     pb0, acc[sub], 0, 0, 0);
            acc[sub] = __builtin_amdgcn_mfma_f32_32x32x16_bf16(va[2 * sub + 1], pb1, acc[sub], 0, 0, 0);
        }
        __builtin_amdgcn_s_setprio(0);
        ka0 = kn0; ka1 = kn1; kl0 = kn2; kl1 = kn3;
    }

    // ---- epilogue: normalize, chunked LDS transpose, coalesced store ----
    float inv = 1.f / lsum;
    float* rwg = rw + ((size_t)bh * NTOT + q0) * FDIM;
#pragma unroll
    for (int c = 0; c < 4; ++c) {
        __syncthreads();
        if (w == c) {
#pragma unroll
            for (int sub = 0; sub < 4; ++sub) {
#pragma unroll
                for (int r = 0; r < 16; ++r) {
                    int fl = sub * 32 + (r & 3) + 8 * (r >> 2) + 4 * hh;
                    ebuf[l31 * 132 + fl] = acc[sub][r] * inv;
                }
            }
        }
        __syncthreads();
        int qr = t >> 3, cb = (t & 7) * 16;
#pragma unroll
        for (int j = 0; j < 4; ++j) {
            *(float4*)&rwg[(size_t)qr * FDIM + c * 128 + cb + j * 4] =
                *(const float4*)&ebuf[qr * 132 + cb + j * 4];
        }
    }
}

// ---------------------------------------------------------------------------
// K5: MFMA GEMM per window: out(64n x 256c) = rwL(64n x 64j) @ Wback(64j x 256c)
__global__ __launch_bounds__(256) void k5_back(
    const float* __restrict__ rw, const unsigned short* __restrict__ Wp,
    float* __restrict__ out) {
    __shared__ unsigned short SB[2 * 64 * 72];   // hi plane, lo plane (18.4 KB)
    unsigned short* BhL = SB;
    unsigned short* BlL = SB + 64 * 72;
    int blk = blockIdx.x;
    int b = blk / NTOT, N = blk % NTOT;
    int src = N / NSRC, nloc = N % NSRC;
    int wh = nloc / 28, ww = nloc % 28;
    int t = threadIdx.x;
    int w = t >> 6, lane = t & 63;
    int lm = lane & 15, lk = lane >> 4;
    int pbase = (b * 224 + wh * 8) * 224 + ww * 8;

#pragma unroll
    for (int i = 0; i < 4; ++i) {
        int flat4 = i * 256 + t;
        int h = flat4 >> 7;
        int f0 = (flat4 & 127) * 4;
        float4 v = *(const float4*)&rw[((size_t)(b * NHD + h) * NTOT + N) * FDIM + f0];
        int n = f0 >> 3;
        int ebase = f0 & 7;
        float vv[4] = {v.x, v.y, v.z, v.w};
#pragma unroll
        for (int u = 0; u < 4; ++u) {
            int j8 = ebase + u;
            unsigned short h16, l16;
            split_bf(vv[u], h16, l16);
            int col = ((j8 ^ (n & 7)) << 3) | h;
            BhL[n * 72 + col] = h16;
            BlL[n * 72 + col] = l16;
        }
    }
    __syncthreads();

    f32x4 acc[4][4];
#pragma unroll
    for (int mi = 0; mi < 4; ++mi)
#pragma unroll
        for (int nt = 0; nt < 4; ++nt) acc[mi][nt] = (f32x4)0.f;

    const unsigned short* Wpw = Wp + (size_t)(w * 4) * 2048 + lane * 8;
#pragma unroll
    for (int kc = 0; kc < 2; ++kc) {
        s16x8 Ah[4], Al[4], Bh4[4], Bl4[4];
#pragma unroll
        for (int mi = 0; mi < 4; ++mi) {
            int base = mi * 2048 + kc * 1024;
            Ah[mi] = *(const s16x8*)&Wpw[base];
            Al[mi] = *(const s16x8*)&Wpw[base + 512];
        }
#pragma unroll
        for (int nt = 0; nt < 4; ++nt) {
            int n = nt * 16 + lm;
            int addr = n * 72 + (((kc * 4 + lk) ^ (n & 7)) << 3);
            Bh4[nt] = *(const s16x8*)&BhL[addr];
            Bl4[nt] = *(const s16x8*)&BlL[addr];
        }
#pragma unroll
        for (int mi = 0; mi < 4; ++mi)
#pragma unroll
            for (int nt = 0; nt < 4; ++nt) {
                acc[mi][nt] = __builtin_amdgcn_mfma_f32_16x16x32_bf16(Ah[mi], Bl4[nt], acc[mi][nt], 0, 0, 0);
                acc[mi][nt] = __builtin_amdgcn_mfma_f32_16x16x32_bf16(Al[mi], Bh4[nt], acc[mi][nt], 0, 0, 0);
                acc[mi][nt] = __builtin_amdgcn_mfma_f32_16x16x32_bf16(Ah[mi], Bh4[nt], acc[mi][nt], 0, 0, 0);
            }
    }

    float* eb = (float*)SB;
    float* outp = out + (size_t)src * OUT_PER_SRC;
#pragma unroll
    for (int ch = 0; ch < 4; ++ch) {
        __syncthreads();
        if (w == ch) {
#pragma unroll
            for (int mi = 0; mi < 4; ++mi)
#pragma unroll
                for (int nt = 0; nt < 4; ++nt)
#pragma unroll
                    for (int r = 0; r < 4; ++r) {
                        int n = nt * 16 + lm;
                        int cl = mi * 16 + lk * 4 + r;
                        eb[n * 68 + cl] = acc[mi][nt][r];
                    }
        }
        __syncthreads();
#pragma unroll
        for (int i = 0; i < 4; ++i) {
            int fl4 = i * 256 + t;
            int n = fl4 >> 4, c4 = (fl4 & 15) * 4;
            int opix = pbase + (n >> 3) * 224 + (n & 7);
            *(float4*)&outp[(size_t)opix * DVC + ch * 64 + c4] =
                *(const float4*)&eb[n * 68 + c4];
        }
    }
}

// ---------------------------------------------------------------------------
extern "C" void kernel_launch(void* const* d_in, const int* in_sizes, int n_in,
                              void* d_out, int out_size, void* d_ws, size_t ws_size,
                              hipStream_t stream) {
    const float* v0   = (const float*)d_in[0];
    const float* c0   = (const float*)d_in[1];
    const float* v1   = (const float*)d_in[2];
    const float* c1   = (const float*)d_in[3];
    const float* Wqkv = (const float*)d_in[4];
    const float* bqkv = (const float*)d_in[5];
    const float* gv   = (const float*)d_in[6];
    const float* Wqkc = (const float*)d_in[7];
    const float* bqkc = (const float*)d_in[8];
    const float* gc   = (const float*)d_in[9];
    const float* Wv   = (const float*)d_in[10];
    const float* Wbk  = (const float*)d_in[11];

    float* ws = (float*)d_ws;
    float* rw   = ws;                        // 12,845,056 fl (aliases Vavg/Cavg)
    float* Vavg = ws;                        //    802,816 fl
    float* Cavg = ws + 802816;               //    200,704 fl
    unsigned short* Qp   = (unsigned short*)(ws + 12845056);  // 1,605,632 u16
    unsigned short* Kp   = (unsigned short*)(ws + 13647872);  // 1,605,632 u16
    unsigned short* Wvp  = (unsigned short*)(ws + 14450688);  //    32,768 u16
    unsigned short* Vvb  = (unsigned short*)(ws + 14467072);  // 12,845,056 u16
    unsigned short* Vp   = (unsigned short*)(ws + 20889600);  // 12,845,056 u16
    unsigned short* Wp   = (unsigned short*)(ws + 27312128);  //    65,536 u16
    // total ends at 27,344,896 fl = 109.4 MB

    float* outp = (float*)d_out;

    kz_zero   <<<1568, 256, 0, stream>>>(Qp);   // zeros Qp+Kp (contiguous)
    k0c_wvpack<<<256, 256, 0, stream>>>(Wv, Wvp);
    k0b_wback <<<256, 256, 0, stream>>>(Wbk, Wp);
    k3_vv     <<<2 * NTOT, 256, 0, stream>>>(v0, v1, Wvp, Vvb, Vavg);
    k1c_avg   <<<784, 256, 0, stream>>>(c0, c1, Cavg);
    k2_qk     <<<2 * NTOT, 256, 0, stream>>>(Vavg, Cavg, Wqkv, bqkv, gv, Wqkc, bqkc, gc, Qp, Kp);
    k3b_pack  <<<dim3(49, 16), 256, 0, stream>>>(Vvb, Vp);
    k4_attn   <<<784, 256, 0, stream>>>(Qp, Kp, Vp, rw);
    k5_back   <<<2 * NTOT, 256, 0, stream>>>(rw, Wp, outp);
}

// Round 17
// 328.402 us; speedup vs baseline: 1.0988x; 1.0371x over previous
//
#include <hip/hip_runtime.h>

#define NSRC 784
#define NTOT 1568
#define NHD 8
#define DVC 256
#define DCC 64
#define D20 20
#define FDIM 512
#define OUT_PER_SRC 25690112

typedef short s16x8 __attribute__((ext_vector_type(8)));
typedef unsigned short u16x8 __attribute__((ext_vector_type(8)));
typedef unsigned short u16x4 __attribute__((ext_vector_type(4)));
typedef float f32x4 __attribute__((ext_vector_type(4)));
typedef float f32x16 __attribute__((ext_vector_type(16)));
typedef unsigned u32x4 __attribute__((ext_vector_type(4)));

#define LOG2E 1.4426950408889634f

__device__ __forceinline__ unsigned short f2bf(float x) {
    unsigned u = __float_as_uint(x);
    unsigned r = (u + 0x7FFFu + ((u >> 16) & 1u)) >> 16;   // RNE
    return (unsigned short)r;
}

__device__ __forceinline__ unsigned cvt_pk_bf16(float lo, float hi) {
    unsigned r;
    asm volatile("v_cvt_pk_bf16_f32 %0, %1, %2" : "=v"(r) : "v"(lo), "v"(hi));
    return r;
}

// native 2^x (single v_exp_f32, no libcall guards, no pre-multiply)
__device__ __forceinline__ float fexp2(float x) {
    float r;
    asm("v_exp_f32 %0, %1" : "=v"(r) : "v"(x));
    return r;
}

// split float into bf16 hi + bf16 lo correction (x ~= hi + lo)
__device__ __forceinline__ void split_bf(float x, unsigned short& hi, unsigned short& lo) {
    unsigned short h = f2bf(x);
    float hf = __uint_as_float(((unsigned)h) << 16);
    hi = h;
    lo = f2bf(x - hf);
}

// v_permlane32_swap_b32: a' = [a.lo32 | b.lo32], b' = [a.hi32 | b.hi32]
__device__ __forceinline__ void permlane32_swap(unsigned& a, unsigned& b) {
    asm volatile("v_permlane32_swap_b32 %0, %1" : "+v"(a), "+v"(b));
}

// ---------------------------------------------------------------------------
// KZ: zero Qp+Kp (contiguous) — clears the d in [20,32) pad slots
__global__ __launch_bounds__(256) void kz_zero(unsigned short* __restrict__ p) {
    size_t i = (size_t)blockIdx.x * 256 + threadIdx.x;
    u16x8 z = (u16x8)0;
    *(u16x8*)&p[i * 8] = z;
}

// ---------------------------------------------------------------------------
// K0c: pack Wv(256dd x 64e) -> A-fragment order hi/lo for k3
__global__ __launch_bounds__(256) void k0c_wvpack(
    const float* __restrict__ Wv, unsigned short* __restrict__ Wvp) {
    int idx = blockIdx.x * 256 + threadIdx.x;        // 0..65535
    int j = idx & 7, lane = (idx >> 3) & 63, hl = (idx >> 9) & 1;
    int c = (idx >> 10) & 7, mi = idx >> 13;
    int e = mi * 16 + (lane & 15);
    int dd = c * 32 + (lane >> 4) * 8 + j;
    unsigned short h, l;
    split_bf(Wv[dd * DCC + e], h, l);
    Wvp[idx] = hl ? l : h;
}

// ---------------------------------------------------------------------------
// K0b: pack Wback(64j x 256c) -> A-fragment order hi/lo
__global__ __launch_bounds__(256) void k0b_wback(
    const float* __restrict__ Wb, unsigned short* __restrict__ Wp) {
    int idx = blockIdx.x * 256 + threadIdx.x;        // 0..65535
    int jj = idx & 7, lane = (idx >> 3) & 63, hl = (idx >> 9) & 1;
    int kc = (idx >> 10) & 1, mt = idx >> 11;
    int c = mt * 16 + (lane & 15);
    int j = kc * 32 + (lane >> 4) * 8 + jj;
    unsigned short h, l;
    split_bf(Wb[j * 256 + c], h, l);
    Wp[idx] = hl ? l : h;
}

// ---------------------------------------------------------------------------
// K1c: window average of coords only
__global__ __launch_bounds__(256) void k1c_avg(
    const float* __restrict__ c0, const float* __restrict__ c1,
    float* __restrict__ Cavg) {
    int wi = blockIdx.x * 4 + (threadIdx.x >> 6);
    int d = threadIdx.x & 63;
    int b = wi / NTOT, N = wi % NTOT;
    int src = N / NSRC, nloc = N % NSRC;
    int wh = nloc / 28, ww = nloc % 28;
    const float* __restrict__ C = src ? c1 : c0;
    int pbase = (b * 224 + wh * 8) * 224 + ww * 8;
    float s = 0.f;
#pragma unroll 8
    for (int p = 0; p < 64; ++p)
        s += C[(size_t)(pbase + (p >> 3) * 224 + (p & 7)) * DCC + d];
    Cavg[(size_t)wi * DCC + d] = s * 0.015625f;
}

// ---------------------------------------------------------------------------
// K2: qk = rmsnorm(avg @ Wqk + b, g); writes Q/K bf16 hi/lo fragments in
// k4's packed lane order. Q pre-scaled by log2(e)/sqrt(I) -> exp2 softmax.
__global__ __launch_bounds__(256) void k2_qk(
    const float* __restrict__ Vavg, const float* __restrict__ Cavg,
    const float* __restrict__ Wqkv, const float* __restrict__ bqkv, const float* __restrict__ gv,
    const float* __restrict__ Wqkc, const float* __restrict__ bqkc, const float* __restrict__ gc,
    unsigned short* __restrict__ Qp, unsigned short* __restrict__ Kp) {
    __shared__ float xv[DVC];
    __shared__ float xc[DCC];
    __shared__ float wred[4];
    int blk = blockIdx.x;
    int b = blk / NTOT, N = blk % NTOT;
    int t = threadIdx.x;
    int tile = N >> 5, l31 = N & 31;
    xv[t] = Vavg[(size_t)blk * DVC + t];
    if (t < DCC) xc[t] = Cavg[(size_t)blk * DCC + t];
    __syncthreads();
    float yv = bqkv[t];
#pragma unroll 4
    for (int d = 0; d < DVC; ++d) yv += xv[d] * Wqkv[d * 256 + t];
    float ss = yv * yv;
#pragma unroll
    for (int off = 32; off; off >>= 1) ss += __shfl_xor(ss, off, 64);
    if ((t & 63) == 0) wred[t >> 6] = ss;
    __syncthreads();
    float tot = wred[0] + wred[1] + wred[2] + wred[3];
    float rv = rsqrtf(tot * (1.f / 256.f) + 1e-6f);
    float yn = yv * rv * gv[t];
    int h = t >> 5, c = t & 31;
    int bh = b * NHD + h;
    {
        int isq = (c < 16);
        int d = isq ? c : c - 16;
        float val = isq ? yn * (0.088388347648318447f * LOG2E) : yn;
        unsigned short h16, l16;
        split_bf(val, h16, l16);
        int hh = d >> 3, j = d & 7;
        size_t base = ((size_t)(bh * 49 + tile) * 4) * 512 + (size_t)(hh * 32 + l31) * 8 + j;
        unsigned short* dst = isq ? Qp : Kp;
        dst[base] = h16;
        dst[base + 1024] = l16;
    }
    if (t < DCC) {
        float yc = bqkc[t];
#pragma unroll 4
        for (int d = 0; d < DCC; ++d) yc += xc[d] * Wqkc[d * 64 + t];
        float sc = yc * yc;
#pragma unroll
        for (int off = 32; off; off >>= 1) sc += __shfl_xor(sc, off, 64);
        float rc = rsqrtf(sc * (1.f / 64.f) + 1e-6f);
        float ycn = yc * rc * gc[t];
        int h2 = t >> 3, c2 = t & 7;
        int bh2 = b * NHD + h2;
        int isq = (c2 < 4);
        int dd = isq ? c2 : c2 - 4;
        float val = isq ? ycn * (0.17677669529663687f * LOG2E) : ycn;
        unsigned short h16, l16;
        split_bf(val, h16, l16);
        size_t base = ((size_t)(bh2 * 49 + tile) * 4 + 1) * 512 + (size_t)l31 * 8 + dd;
        unsigned short* dst = isq ? Qp : Kp;
        dst[base] = h16;
        dst[base + 1024] = l16;
    }
}

// ---------------------------------------------------------------------------
// K3: per-window GEMM as D[e][px] = W^T @ X^T — zero-LDS, zero-barrier main
// loop. (unchanged from R10)
__global__ __launch_bounds__(256) void k3_vv(
    const float* __restrict__ v0, const float* __restrict__ v1,
    const unsigned short* __restrict__ Wvp,
    unsigned short* __restrict__ Vvb, float* __restrict__ Vavg) {
    __shared__ unsigned short eb[64 * 66];   // 8.4 KB
    __shared__ float avgw[1024];             // 4 KB
    int blk = blockIdx.x;
    int b = blk / NTOT, N = blk % NTOT;
    int src = N / NSRC, nloc = N % NSRC;
    int wh = nloc / 28, ww = nloc % 28;
    const float* __restrict__ V = src ? v1 : v0;
    int t = threadIdx.x;
    int w = t >> 6, lane = t & 63;
    int lm = lane & 15, lk = lane >> 4;
    int px = w * 16 + lm;
    int pbase = (b * 224 + wh * 8) * 224 + ww * 8;
    const float* __restrict__ xrow =
        V + (size_t)(pbase + (px >> 3) * 224 + (px & 7)) * DVC + lk * 8;

    f32x4 acc[4];
#pragma unroll
    for (int mi = 0; mi < 4; ++mi) acc[mi] = (f32x4)0.f;

#pragma unroll
    for (int c = 0; c < 8; ++c) {
        float4 x0 = *(const float4*)&xrow[c * 32];
        float4 x1 = *(const float4*)&xrow[c * 32 + 4];
        float xv8[8] = {x0.x, x0.y, x0.z, x0.w, x1.x, x1.y, x1.z, x1.w};
        u16x8 bhu, blu;
#pragma unroll
        for (int j = 0; j < 8; ++j) {
            unsigned short hq, lq;
            split_bf(xv8[j], hq, lq);
            bhu[j] = hq; blu[j] = lq;
        }
        s16x8 xhi = __builtin_bit_cast(s16x8, bhu);
        s16x8 xlo = __builtin_bit_cast(s16x8, blu);
        float sv[8] = {xv8[0], xv8[1], xv8[2], xv8[3], xv8[4], xv8[5], xv8[6], xv8[7]};
#pragma unroll
        for (int off = 1; off <= 8; off <<= 1)
#pragma unroll
            for (int j = 0; j < 8; ++j) sv[j] += __shfl_xor(sv[j], off, 64);
        if (lm == 0) {
#pragma unroll
            for (int j = 0; j < 8; ++j)
                avgw[w * 256 + c * 32 + lk * 8 + j] = sv[j];
        }
#pragma unroll
        for (int mi = 0; mi < 4; ++mi) {
            const unsigned short* Wf = Wvp + (size_t)((mi * 8 + c) * 2) * 512 + lane * 8;
            s16x8 Ah = *(const s16x8*)&Wf[0];
            s16x8 Al = *(const s16x8*)&Wf[512];
            acc[mi] = __builtin_amdgcn_mfma_f32_16x16x32_bf16(Ah, xlo, acc[mi], 0, 0, 0);
            acc[mi] = __builtin_amdgcn_mfma_f32_16x16x32_bf16(Al, xhi, acc[mi], 0, 0, 0);
            acc[mi] = __builtin_amdgcn_mfma_f32_16x16x32_bf16(Ah, xhi, acc[mi], 0, 0, 0);
        }
    }
#pragma unroll
    for (int mi = 0; mi < 4; ++mi) {
#pragma unroll
        for (int r = 0; r < 4; ++r) {
            int e = mi * 16 + lk * 4 + r;
            eb[px * 66 + e] = f2bf(acc[mi][r]);
        }
    }
    __syncthreads();
    unsigned short* dst = Vvb + (size_t)blk * 4096;
#pragma unroll
    for (int i = 0; i < 2; ++i) {
        int flat16 = i * 256 + t;            // 0..511
        int f3 = flat16 >> 6;
        int h = (flat16 >> 3) & 7;
        int px8 = (flat16 & 7) * 8;
        u16x8 vv;
#pragma unroll
        for (int u = 0; u < 8; ++u) vv[u] = eb[(px8 + u) * 66 + f3 * 8 + h];
        *(u16x8*)&dst[flat16 * 8] = vv;
    }
    Vavg[(size_t)blk * DVC + t] =
        (avgw[t] + avgw[256 + t] + avgw[512 + t] + avgw[768 + t]) * 0.015625f;
}

// ---------------------------------------------------------------------------
// K3b: pack Vvb [b][N][f3][h][px] -> Vp fragment order (unchanged)
__global__ __launch_bounds__(256) void k3b_pack(
    const unsigned short* __restrict__ Vvb, unsigned short* __restrict__ Vp) {
    __shared__ unsigned short tile[32 * 576];   // [N][f3][72]
    int kt = blockIdx.x, bh = blockIdx.y;
    int b = bh >> 3, h = bh & 7;
    int t = threadIdx.x;
#pragma unroll
    for (int it = 0; it < 8; ++it) {
        int flat = it * 256 + t;                // 0..2047
        int r5 = flat >> 6;
        int c = flat & 63;
        int f3 = c >> 3, px8 = (c & 7) * 8;
        const unsigned short* s =
            Vvb + ((size_t)(b * NTOT + kt * 32 + r5) * 8 + f3) * 512 + h * 64 + px8;
        *(u16x8*)&tile[r5 * 576 + f3 * 72 + px8] = *(const u16x8*)s;
    }
    __syncthreads();
    unsigned short* dst = Vp + ((size_t)bh * 49 + kt) * 16384;
#pragma unroll
    for (int it = 0; it < 8; ++it) {
        int flato = it * 256 + t;
        int lane = flato & 63;
        int kh = (flato >> 6) & 1;
        int sub = (flato >> 7) & 3;
        int w = flato >> 9;
        int l31 = lane & 31, hh = lane >> 5;
        int f = w * 128 + sub * 32 + l31;
        int kbase = kh * 16 + hh * 8;
        u16x8 v;
#pragma unroll
        for (int j = 0; j < 8; ++j)
            v[j] = tile[(kbase + j) * 576 + (f & 7) * 72 + (f >> 3)];
        *(u16x8*)&dst[(size_t)flato * 8] = v;
    }
}

// ---------------------------------------------------------------------------
// K4: flash attention — R14 wave-level structure, R17 block split: 128-thread
// blocks (2 waves, 256-f half each), grid 1568 for CU load balance. No setprio.
__global__ __launch_bounds__(128) void k4_attn(
    const unsigned short* __restrict__ Qp, const unsigned short* __restrict__ Kp,
    const unsigned short* __restrict__ Vp, float* __restrict__ rw) {
    __shared__ float ebuf[32 * 132];
    int wg = blockIdx.x;
    int bh = wg & 15;                     // wg%8 == bh%8 -> XCD affinity
    int fh = (wg >> 4) & 1;               // feature half
    int qt = wg >> 5;
    int q0 = qt * 32;
    int t = threadIdx.x;
    int w = t >> 6, lane = t & 63;        // w in {0,1}
    int l31 = lane & 31, hh = lane >> 5;

    const unsigned short* __restrict__ Qpb = Qp + ((size_t)(bh * 49 + qt) * 4) * 512 + lane * 8;
    const unsigned short* __restrict__ Kpb = Kp + (size_t)bh * 49 * 2048 + lane * 8;
    const unsigned short* __restrict__ Vpb = Vp + (size_t)bh * 49 * 16384 + lane * 8;
    int wq = fh * 2 + w;                  // quarter index in Vp layout (0..3)

    s16x8 qa0 = *(const s16x8*)&Qpb[0];
    s16x8 qa1 = *(const s16x8*)&Qpb[512];
    s16x8 ql0 = *(const s16x8*)&Qpb[1024];
    s16x8 ql1 = *(const s16x8*)&Qpb[1536];

    // K fragments for tile 0 (cross-tile prefetch registers)
    s16x8 ka0 = *(const s16x8*)&Kpb[0];
    s16x8 ka1 = *(const s16x8*)&Kpb[512];
    s16x8 kl0 = *(const s16x8*)&Kpb[1024];
    s16x8 kl1 = *(const s16x8*)&Kpb[1536];

    float m = -1e30f, lsum = 0.f;
    f32x16 acc[4];
#pragma unroll
    for (int s = 0; s < 4; ++s) acc[s] = (f32x16)0.f;

    for (int kt = 0; kt < NTOT / 32; ++kt) {
        // ---- V fragment loads (consumed last) ----
        const unsigned short* Vtile = Vpb + (size_t)kt * 16384 + (wq * 8) * 512;
        s16x8 va[8];
#pragma unroll
        for (int fr = 0; fr < 8; ++fr)
            va[fr] = *(const s16x8*)&Vtile[fr * 512];
        // ---- prefetch next K tile ----
        int ktn = (kt < 48) ? kt + 1 : 48;
        const unsigned short* Ktn = Kpb + (size_t)ktn * 2048;
        s16x8 kn0 = *(const s16x8*)&Ktn[0];
        s16x8 kn1 = *(const s16x8*)&Ktn[512];
        s16x8 kn2 = *(const s16x8*)&Ktn[1024];
        s16x8 kn3 = *(const s16x8*)&Ktn[1536];

        // ---- S^T = K @ Q^T (32k x 32q), 3-term hi/lo, exp2 domain ----
        f32x16 sacc = (f32x16)0.f;
        sacc = __builtin_amdgcn_mfma_f32_32x32x16_bf16(kl0, qa0, sacc, 0, 0, 0);
        sacc = __builtin_amdgcn_mfma_f32_32x32x16_bf16(ka0, ql0, sacc, 0, 0, 0);
        sacc = __builtin_amdgcn_mfma_f32_32x32x16_bf16(ka0, qa0, sacc, 0, 0, 0);
        sacc = __builtin_amdgcn_mfma_f32_32x32x16_bf16(kl1, qa1, sacc, 0, 0, 0);
        sacc = __builtin_amdgcn_mfma_f32_32x32x16_bf16(ka1, ql1, sacc, 0, 0, 0);
        sacc = __builtin_amdgcn_mfma_f32_32x32x16_bf16(ka1, qa1, sacc, 0, 0, 0);

        // ---- online softmax stats (log2 domain), max3-fused tree ----
        float t0 = fmaxf(fmaxf(sacc[0], sacc[1]), sacc[2]);
        float t1 = fmaxf(fmaxf(sacc[3], sacc[4]), sacc[5]);
        float t2 = fmaxf(fmaxf(sacc[6], sacc[7]), sacc[8]);
        float t3 = fmaxf(fmaxf(sacc[9], sacc[10]), sacc[11]);
        float t4 = fmaxf(fmaxf(sacc[12], sacc[13]), sacc[14]);
        float u0 = fmaxf(fmaxf(t0, t1), t2);
        float u1 = fmaxf(t3, t4);
        float tmax = fmaxf(fmaxf(u0, u1), sacc[15]);
        tmax = fmaxf(tmax, __shfl_xor(tmax, 32, 64));
        if (__any(tmax > m + 11.5f)) {        // defer-max, log2 units (~e^8)
            float mn = fmaxf(m, tmax);
            float sc = fexp2(m - mn);
#pragma unroll
            for (int s = 0; s < 4; ++s) acc[s] = acc[s] * sc;
            lsum *= sc;
            m = mn;
        }
        // ---- P = 2^(S - m) (single v_exp each), pack bf16 pairs ----
        unsigned P2[8];
        float ts0 = 0.f, ts1 = 0.f;
#pragma unroll
        for (int j = 0; j < 8; ++j) {
            float pa = fexp2(sacc[2 * j] - m);
            float pb = fexp2(sacc[2 * j + 1] - m);
            ts0 += pa; ts1 += pb;
            P2[j] = cvt_pk_bf16(pa, pb);
        }
        float tsum = ts0 + ts1;
        lsum += tsum + __shfl_xor(tsum, 32, 64);
        // ---- half-exchange via permlane32_swap ----
        permlane32_swap(P2[0], P2[2]);
        permlane32_swap(P2[1], P2[3]);
        permlane32_swap(P2[4], P2[6]);
        permlane32_swap(P2[5], P2[7]);
        u32x4 b0u, b1u;
        b0u[0] = P2[0]; b0u[1] = P2[1]; b0u[2] = P2[2]; b0u[3] = P2[3];
        b1u[0] = P2[4]; b1u[1] = P2[5]; b1u[2] = P2[6]; b1u[3] = P2[7];
        s16x8 pb0 = __builtin_bit_cast(s16x8, b0u);
        s16x8 pb1 = __builtin_bit_cast(s16x8, b1u);

        // ---- PV: O^T[f][q] += V^T[f][k] P^T[k][q] ----
#pragma unroll
        for (int sub = 0; sub < 4; ++sub) {
            acc[sub] = __builtin_amdgcn_mfma_f32_32x32x16_bf16(va[2 * sub],     pb0, acc[sub], 0, 0, 0);
            acc[sub] = __builtin_amdgcn_mfma_f32_32x32x16_bf16(va[2 * sub + 1], pb1, acc[sub], 0, 0, 0);
        }
        ka0 = kn0; ka1 = kn1; kl0 = kn2; kl1 = kn3;
    }

    // ---- epilogue: normalize, 2-chunk LDS transpose, coalesced store ----
    float inv = 1.f / lsum;
    float* rwg = rw + ((size_t)bh * NTOT + q0) * FDIM + fh * 256;
#pragma unroll
    for (int c = 0; c < 2; ++c) {
        __syncthreads();
        if (w == c) {
#pragma unroll
            for (int sub = 0; sub < 4; ++sub) {
#pragma unroll
                for (int r = 0; r < 16; ++r) {
                    int fl = sub * 32 + (r & 3) + 8 * (r >> 2) + 4 * hh;
                    ebuf[l31 * 132 + fl] = acc[sub][r] * inv;
                }
            }
        }
        __syncthreads();
        int qr = t >> 2, cb = (t & 3) * 32;
#pragma unroll
        for (int j = 0; j < 8; ++j) {
            *(float4*)&rwg[(size_t)qr * FDIM + c * 128 + cb + j * 4] =
                *(const float4*)&ebuf[qr * 132 + cb + j * 4];
        }
    }
}

// ---------------------------------------------------------------------------
// K5: MFMA GEMM per window: out(64n x 256c) = rwL(64n x 64j) @ Wback(64j x 256c)
__global__ __launch_bounds__(256) void k5_back(
    const float* __restrict__ rw, const unsigned short* __restrict__ Wp,
    float* __restrict__ out) {
    __shared__ unsigned short SB[2 * 64 * 72];   // hi plane, lo plane (18.4 KB)
    unsigned short* BhL = SB;
    unsigned short* BlL = SB + 64 * 72;
    int blk = blockIdx.x;
    int b = blk / NTOT, N = blk % NTOT;
    int src = N / NSRC, nloc = N % NSRC;
    int wh = nloc / 28, ww = nloc % 28;
    int t = threadIdx.x;
    int w = t >> 6, lane = t & 63;
    int lm = lane & 15, lk = lane >> 4;
    int pbase = (b * 224 + wh * 8) * 224 + ww * 8;

#pragma unroll
    for (int i = 0; i < 4; ++i) {
        int flat4 = i * 256 + t;
        int h = flat4 >> 7;
        int f0 = (flat4 & 127) * 4;
        float4 v = *(const float4*)&rw[((size_t)(b * NHD + h) * NTOT + N) * FDIM + f0];
        int n = f0 >> 3;
        int ebase = f0 & 7;
        float vv[4] = {v.x, v.y, v.z, v.w};
#pragma unroll
        for (int u = 0; u < 4; ++u) {
            int j8 = ebase + u;
            unsigned short h16, l16;
            split_bf(vv[u], h16, l16);
            int col = ((j8 ^ (n & 7)) << 3) | h;
            BhL[n * 72 + col] = h16;
            BlL[n * 72 + col] = l16;
        }
    }
    __syncthreads();

    f32x4 acc[4][4];
#pragma unroll
    for (int mi = 0; mi < 4; ++mi)
#pragma unroll
        for (int nt = 0; nt < 4; ++nt) acc[mi][nt] = (f32x4)0.f;

    const unsigned short* Wpw = Wp + (size_t)(w * 4) * 2048 + lane * 8;
#pragma unroll
    for (int kc = 0; kc < 2; ++kc) {
        s16x8 Ah[4], Al[4], Bh4[4], Bl4[4];
#pragma unroll
        for (int mi = 0; mi < 4; ++mi) {
            int base = mi * 2048 + kc * 1024;
            Ah[mi] = *(const s16x8*)&Wpw[base];
            Al[mi] = *(const s16x8*)&Wpw[base + 512];
        }
#pragma unroll
        for (int nt = 0; nt < 4; ++nt) {
            int n = nt * 16 + lm;
            int addr = n * 72 + (((kc * 4 + lk) ^ (n & 7)) << 3);
            Bh4[nt] = *(const s16x8*)&BhL[addr];
            Bl4[nt] = *(const s16x8*)&BlL[addr];
        }
#pragma unroll
        for (int mi = 0; mi < 4; ++mi)
#pragma unroll
            for (int nt = 0; nt < 4; ++nt) {
                acc[mi][nt] = __builtin_amdgcn_mfma_f32_16x16x32_bf16(Ah[mi], Bl4[nt], acc[mi][nt], 0, 0, 0);
                acc[mi][nt] = __builtin_amdgcn_mfma_f32_16x16x32_bf16(Al[mi], Bh4[nt], acc[mi][nt], 0, 0, 0);
                acc[mi][nt] = __builtin_amdgcn_mfma_f32_16x16x32_bf16(Ah[mi], Bh4[nt], acc[mi][nt], 0, 0, 0);
            }
    }

    float* eb = (float*)SB;
    float* outp = out + (size_t)src * OUT_PER_SRC;
#pragma unroll
    for (int ch = 0; ch < 4; ++ch) {
        __syncthreads();
        if (w == ch) {
#pragma unroll
            for (int mi = 0; mi < 4; ++mi)
#pragma unroll
                for (int nt = 0; nt < 4; ++nt)
#pragma unroll
                    for (int r = 0; r < 4; ++r) {
                        int n = nt * 16 + lm;
                        int cl = mi * 16 + lk * 4 + r;
                        eb[n * 68 + cl] = acc[mi][nt][r];
                    }
        }
        __syncthreads();
#pragma unroll
        for (int i = 0; i < 4; ++i) {
            int fl4 = i * 256 + t;
            int n = fl4 >> 4, c4 = (fl4 & 15) * 4;
            int opix = pbase + (n >> 3) * 224 + (n & 7);
            *(float4*)&outp[(size_t)opix * DVC + ch * 64 + c4] =
                *(const float4*)&eb[n * 68 + c4];
        }
    }
}

// ---------------------------------------------------------------------------
extern "C" void kernel_launch(void* const* d_in, const int* in_sizes, int n_in,
                              void* d_out, int out_size, void* d_ws, size_t ws_size,
                              hipStream_t stream) {
    const float* v0   = (const float*)d_in[0];
    const float* c0   = (const float*)d_in[1];
    const float* v1   = (const float*)d_in[2];
    const float* c1   = (const float*)d_in[3];
    const float* Wqkv = (const float*)d_in[4];
    const float* bqkv = (const float*)d_in[5];
    const float* gv   = (const float*)d_in[6];
    const float* Wqkc = (const float*)d_in[7];
    const float* bqkc = (const float*)d_in[8];
    const float* gc   = (const float*)d_in[9];
    const float* Wv   = (const float*)d_in[10];
    const float* Wbk  = (const float*)d_in[11];

    float* ws = (float*)d_ws;
    float* rw   = ws;                        // 12,845,056 fl (aliases Vavg/Cavg)
    float* Vavg = ws;                        //    802,816 fl
    float* Cavg = ws + 802816;               //    200,704 fl
    unsigned short* Qp   = (unsigned short*)(ws + 12845056);  // 1,605,632 u16
    unsigned short* Kp   = (unsigned short*)(ws + 13647872);  // 1,605,632 u16
    unsigned short* Wvp  = (unsigned short*)(ws + 14450688);  //    32,768 u16
    unsigned short* Vvb  = (unsigned short*)(ws + 14467072);  // 12,845,056 u16
    unsigned short* Vp   = (unsigned short*)(ws + 20889600);  // 12,845,056 u16
    unsigned short* Wp   = (unsigned short*)(ws + 27312128);  //    65,536 u16
    // total ends at 27,344,896 fl = 109.4 MB

    float* outp = (float*)d_out;

    kz_zero   <<<1568, 256, 0, stream>>>(Qp);   // zeros Qp+Kp (contiguous)
    k0c_wvpack<<<256, 256, 0, stream>>>(Wv, Wvp);
    k0b_wback <<<256, 256, 0, stream>>>(Wbk, Wp);
    k3_vv     <<<2 * NTOT, 256, 0, stream>>>(v0, v1, Wvp, Vvb, Vavg);
    k1c_avg   <<<784, 256, 0, stream>>>(c0, c1, Cavg);
    k2_qk     <<<2 * NTOT, 256, 0, stream>>>(Vavg, Cavg, Wqkv, bqkv, gv, Wqkc, bqkc, gc, Qp, Kp);
    k3b_pack  <<<dim3(49, 16), 256, 0, stream>>>(Vvb, Vp);
    k4_attn   <<<1568, 128, 0, stream>>>(Qp, Kp, Vp, rw);
    k5_back   <<<2 * NTOT, 256, 0, stream>>>(rw, Wp, outp);
}

// Round 18
// 327.301 us; speedup vs baseline: 1.1025x; 1.0034x over previous
//
#include <hip/hip_runtime.h>

#define NSRC 784
#define NTOT 1568
#define NHD 8
#define DVC 256
#define DCC 64
#define D20 20
#define FDIM 512
#define OUT_PER_SRC 25690112

typedef short s16x8 __attribute__((ext_vector_type(8)));
typedef unsigned short u16x8 __attribute__((ext_vector_type(8)));
typedef unsigned short u16x4 __attribute__((ext_vector_type(4)));
typedef float f32x4 __attribute__((ext_vector_type(4)));
typedef float f32x16 __attribute__((ext_vector_type(16)));
typedef unsigned u32x4 __attribute__((ext_vector_type(4)));

#define LOG2E 1.4426950408889634f

__device__ __forceinline__ unsigned short f2bf(float x) {
    unsigned u = __float_as_uint(x);
    unsigned r = (u + 0x7FFFu + ((u >> 16) & 1u)) >> 16;   // RNE
    return (unsigned short)r;
}

__device__ __forceinline__ unsigned cvt_pk_bf16(float lo, float hi) {
    unsigned r;
    asm volatile("v_cvt_pk_bf16_f32 %0, %1, %2" : "=v"(r) : "v"(lo), "v"(hi));
    return r;
}

// native 2^x (single v_exp_f32, no libcall guards, no pre-multiply)
__device__ __forceinline__ float fexp2(float x) {
    float r;
    asm("v_exp_f32 %0, %1" : "=v"(r) : "v"(x));
    return r;
}

// split float into bf16 hi + bf16 lo correction (x ~= hi + lo)
__device__ __forceinline__ void split_bf(float x, unsigned short& hi, unsigned short& lo) {
    unsigned short h = f2bf(x);
    float hf = __uint_as_float(((unsigned)h) << 16);
    hi = h;
    lo = f2bf(x - hf);
}

// pair split via v_cvt_pk: wh = packed bf16 hi of (x0,x1); wl = packed lo
// residuals. Identity x ~= hif + lof holds for any hi rounding (lo is
// computed from the exact float residual).
__device__ __forceinline__ void split_pk2(float x0, float x1,
                                          unsigned& wh, unsigned& wl) {
    wh = cvt_pk_bf16(x0, x1);
    float h0 = __uint_as_float(wh << 16);
    float h1 = __uint_as_float(wh & 0xffff0000u);
    wl = cvt_pk_bf16(x0 - h0, x1 - h1);
}

// v_permlane32_swap_b32: a' = [a.lo32 | b.lo32], b' = [a.hi32 | b.hi32]
__device__ __forceinline__ void permlane32_swap(unsigned& a, unsigned& b) {
    asm volatile("v_permlane32_swap_b32 %0, %1" : "+v"(a), "+v"(b));
}

// ---------------------------------------------------------------------------
// KZ: zero Qp+Kp (contiguous) — clears the d in [20,32) pad slots
__global__ __launch_bounds__(256) void kz_zero(unsigned short* __restrict__ p) {
    size_t i = (size_t)blockIdx.x * 256 + threadIdx.x;
    u16x8 z = (u16x8)0;
    *(u16x8*)&p[i * 8] = z;
}

// ---------------------------------------------------------------------------
// K0c: pack Wv(256dd x 64e) -> A-fragment order hi/lo for k3
__global__ __launch_bounds__(256) void k0c_wvpack(
    const float* __restrict__ Wv, unsigned short* __restrict__ Wvp) {
    int idx = blockIdx.x * 256 + threadIdx.x;        // 0..65535
    int j = idx & 7, lane = (idx >> 3) & 63, hl = (idx >> 9) & 1;
    int c = (idx >> 10) & 7, mi = idx >> 13;
    int e = mi * 16 + (lane & 15);
    int dd = c * 32 + (lane >> 4) * 8 + j;
    unsigned short h, l;
    split_bf(Wv[dd * DCC + e], h, l);
    Wvp[idx] = hl ? l : h;
}

// ---------------------------------------------------------------------------
// K0b: pack Wback(64j x 256c) -> A-fragment order hi/lo
__global__ __launch_bounds__(256) void k0b_wback(
    const float* __restrict__ Wb, unsigned short* __restrict__ Wp) {
    int idx = blockIdx.x * 256 + threadIdx.x;        // 0..65535
    int jj = idx & 7, lane = (idx >> 3) & 63, hl = (idx >> 9) & 1;
    int kc = (idx >> 10) & 1, mt = idx >> 11;
    int c = mt * 16 + (lane & 15);
    int j = kc * 32 + (lane >> 4) * 8 + jj;
    unsigned short h, l;
    split_bf(Wb[j * 256 + c], h, l);
    Wp[idx] = hl ? l : h;
}

// ---------------------------------------------------------------------------
// K1c: window average of coords only
__global__ __launch_bounds__(256) void k1c_avg(
    const float* __restrict__ c0, const float* __restrict__ c1,
    float* __restrict__ Cavg) {
    int wi = blockIdx.x * 4 + (threadIdx.x >> 6);
    int d = threadIdx.x & 63;
    int b = wi / NTOT, N = wi % NTOT;
    int src = N / NSRC, nloc = N % NSRC;
    int wh = nloc / 28, ww = nloc % 28;
    const float* __restrict__ C = src ? c1 : c0;
    int pbase = (b * 224 + wh * 8) * 224 + ww * 8;
    float s = 0.f;
#pragma unroll 8
    for (int p = 0; p < 64; ++p)
        s += C[(size_t)(pbase + (p >> 3) * 224 + (p & 7)) * DCC + d];
    Cavg[(size_t)wi * DCC + d] = s * 0.015625f;
}

// ---------------------------------------------------------------------------
// K2: qk = rmsnorm(avg @ Wqk + b, g); writes Q/K bf16 hi/lo fragments in
// k4's packed lane order. Q pre-scaled by log2(e)/sqrt(I) -> exp2 softmax.
__global__ __launch_bounds__(256) void k2_qk(
    const float* __restrict__ Vavg, const float* __restrict__ Cavg,
    const float* __restrict__ Wqkv, const float* __restrict__ bqkv, const float* __restrict__ gv,
    const float* __restrict__ Wqkc, const float* __restrict__ bqkc, const float* __restrict__ gc,
    unsigned short* __restrict__ Qp, unsigned short* __restrict__ Kp) {
    __shared__ float xv[DVC];
    __shared__ float xc[DCC];
    __shared__ float wred[4];
    int blk = blockIdx.x;
    int b = blk / NTOT, N = blk % NTOT;
    int t = threadIdx.x;
    int tile = N >> 5, l31 = N & 31;
    xv[t] = Vavg[(size_t)blk * DVC + t];
    if (t < DCC) xc[t] = Cavg[(size_t)blk * DCC + t];
    __syncthreads();
    float yv = bqkv[t];
#pragma unroll 4
    for (int d = 0; d < DVC; ++d) yv += xv[d] * Wqkv[d * 256 + t];
    float ss = yv * yv;
#pragma unroll
    for (int off = 32; off; off >>= 1) ss += __shfl_xor(ss, off, 64);
    if ((t & 63) == 0) wred[t >> 6] = ss;
    __syncthreads();
    float tot = wred[0] + wred[1] + wred[2] + wred[3];
    float rv = rsqrtf(tot * (1.f / 256.f) + 1e-6f);
    float yn = yv * rv * gv[t];
    int h = t >> 5, c = t & 31;
    int bh = b * NHD + h;
    {
        int isq = (c < 16);
        int d = isq ? c : c - 16;
        float val = isq ? yn * (0.088388347648318447f * LOG2E) : yn;
        unsigned short h16, l16;
        split_bf(val, h16, l16);
        int hh = d >> 3, j = d & 7;
        size_t base = ((size_t)(bh * 49 + tile) * 4) * 512 + (size_t)(hh * 32 + l31) * 8 + j;
        unsigned short* dst = isq ? Qp : Kp;
        dst[base] = h16;
        dst[base + 1024] = l16;
    }
    if (t < DCC) {
        float yc = bqkc[t];
#pragma unroll 4
        for (int d = 0; d < DCC; ++d) yc += xc[d] * Wqkc[d * 64 + t];
        float sc = yc * yc;
#pragma unroll
        for (int off = 32; off; off >>= 1) sc += __shfl_xor(sc, off, 64);
        float rc = rsqrtf(sc * (1.f / 64.f) + 1e-6f);
        float ycn = yc * rc * gc[t];
        int h2 = t >> 3, c2 = t & 7;
        int bh2 = b * NHD + h2;
        int isq = (c2 < 4);
        int dd = isq ? c2 : c2 - 4;
        float val = isq ? ycn * (0.17677669529663687f * LOG2E) : ycn;
        unsigned short h16, l16;
        split_bf(val, h16, l16);
        size_t base = ((size_t)(bh2 * 49 + tile) * 4 + 1) * 512 + (size_t)l31 * 8 + dd;
        unsigned short* dst = isq ? Qp : Kp;
        dst[base] = h16;
        dst[base + 1024] = l16;
    }
}

// ---------------------------------------------------------------------------
// K3: per-window GEMM as D[e][px] = W^T @ X^T — zero-LDS, zero-barrier main
// loop. R18: pair-packed hi/lo split via v_cvt_pk (6 ops/pair vs 14).
__global__ __launch_bounds__(256) void k3_vv(
    const float* __restrict__ v0, const float* __restrict__ v1,
    const unsigned short* __restrict__ Wvp,
    unsigned short* __restrict__ Vvb, float* __restrict__ Vavg) {
    __shared__ unsigned short eb[64 * 66];   // 8.4 KB
    __shared__ float avgw[1024];             // 4 KB
    int blk = blockIdx.x;
    int b = blk / NTOT, N = blk % NTOT;
    int src = N / NSRC, nloc = N % NSRC;
    int wh = nloc / 28, ww = nloc % 28;
    const float* __restrict__ V = src ? v1 : v0;
    int t = threadIdx.x;
    int w = t >> 6, lane = t & 63;
    int lm = lane & 15, lk = lane >> 4;
    int px = w * 16 + lm;
    int pbase = (b * 224 + wh * 8) * 224 + ww * 8;
    const float* __restrict__ xrow =
        V + (size_t)(pbase + (px >> 3) * 224 + (px & 7)) * DVC + lk * 8;

    f32x4 acc[4];
#pragma unroll
    for (int mi = 0; mi < 4; ++mi) acc[mi] = (f32x4)0.f;

#pragma unroll
    for (int c = 0; c < 8; ++c) {
        float4 x0 = *(const float4*)&xrow[c * 32];
        float4 x1 = *(const float4*)&xrow[c * 32 + 4];
        float xv8[8] = {x0.x, x0.y, x0.z, x0.w, x1.x, x1.y, x1.z, x1.w};
        // ---- pair-packed hi/lo split (cvt_pk) ----
        u32x4 hw, lw;
#pragma unroll
        for (int p = 0; p < 4; ++p) {
            unsigned wh2, wl2;
            split_pk2(xv8[2 * p], xv8[2 * p + 1], wh2, wl2);
            hw[p] = wh2; lw[p] = wl2;
        }
        s16x8 xhi = __builtin_bit_cast(s16x8, hw);
        s16x8 xlo = __builtin_bit_cast(s16x8, lw);
        float sv[8] = {xv8[0], xv8[1], xv8[2], xv8[3], xv8[4], xv8[5], xv8[6], xv8[7]};
#pragma unroll
        for (int off = 1; off <= 8; off <<= 1)
#pragma unroll
            for (int j = 0; j < 8; ++j) sv[j] += __shfl_xor(sv[j], off, 64);
        if (lm == 0) {
#pragma unroll
            for (int j = 0; j < 8; ++j)
                avgw[w * 256 + c * 32 + lk * 8 + j] = sv[j];
        }
#pragma unroll
        for (int mi = 0; mi < 4; ++mi) {
            const unsigned short* Wf = Wvp + (size_t)((mi * 8 + c) * 2) * 512 + lane * 8;
            s16x8 Ah = *(const s16x8*)&Wf[0];
            s16x8 Al = *(const s16x8*)&Wf[512];
            acc[mi] = __builtin_amdgcn_mfma_f32_16x16x32_bf16(Ah, xlo, acc[mi], 0, 0, 0);
            acc[mi] = __builtin_amdgcn_mfma_f32_16x16x32_bf16(Al, xhi, acc[mi], 0, 0, 0);
            acc[mi] = __builtin_amdgcn_mfma_f32_16x16x32_bf16(Ah, xhi, acc[mi], 0, 0, 0);
        }
    }
#pragma unroll
    for (int mi = 0; mi < 4; ++mi) {
#pragma unroll
        for (int r = 0; r < 4; ++r) {
            int e = mi * 16 + lk * 4 + r;
            eb[px * 66 + e] = f2bf(acc[mi][r]);
        }
    }
    __syncthreads();
    unsigned short* dst = Vvb + (size_t)blk * 4096;
#pragma unroll
    for (int i = 0; i < 2; ++i) {
        int flat16 = i * 256 + t;            // 0..511
        int f3 = flat16 >> 6;
        int h = (flat16 >> 3) & 7;
        int px8 = (flat16 & 7) * 8;
        u16x8 vv;
#pragma unroll
        for (int u = 0; u < 8; ++u) vv[u] = eb[(px8 + u) * 66 + f3 * 8 + h];
        *(u16x8*)&dst[flat16 * 8] = vv;
    }
    Vavg[(size_t)blk * DVC + t] =
        (avgw[t] + avgw[256 + t] + avgw[512 + t] + avgw[768 + t]) * 0.015625f;
}

// ---------------------------------------------------------------------------
// K3b: pack Vvb [b][N][f3][h][px] -> Vp fragment order (unchanged)
__global__ __launch_bounds__(256) void k3b_pack(
    const unsigned short* __restrict__ Vvb, unsigned short* __restrict__ Vp) {
    __shared__ unsigned short tile[32 * 576];   // [N][f3][72]
    int kt = blockIdx.x, bh = blockIdx.y;
    int b = bh >> 3, h = bh & 7;
    int t = threadIdx.x;
#pragma unroll
    for (int it = 0; it < 8; ++it) {
        int flat = it * 256 + t;                // 0..2047
        int r5 = flat >> 6;
        int c = flat & 63;
        int f3 = c >> 3, px8 = (c & 7) * 8;
        const unsigned short* s =
            Vvb + ((size_t)(b * NTOT + kt * 32 + r5) * 8 + f3) * 512 + h * 64 + px8;
        *(u16x8*)&tile[r5 * 576 + f3 * 72 + px8] = *(const u16x8*)s;
    }
    __syncthreads();
    unsigned short* dst = Vp + ((size_t)bh * 49 + kt) * 16384;
#pragma unroll
    for (int it = 0; it < 8; ++it) {
        int flato = it * 256 + t;
        int lane = flato & 63;
        int kh = (flato >> 6) & 1;
        int sub = (flato >> 7) & 3;
        int w = flato >> 9;
        int l31 = lane & 31, hh = lane >> 5;
        int f = w * 128 + sub * 32 + l31;
        int kbase = kh * 16 + hh * 8;
        u16x8 v;
#pragma unroll
        for (int j = 0; j < 8; ++j)
            v[j] = tile[(kbase + j) * 576 + (f & 7) * 72 + (f >> 3)];
        *(u16x8*)&dst[(size_t)flato * 8] = v;
    }
}

// ---------------------------------------------------------------------------
// K4: flash attention — R17 structure (128-thread blocks, 2 waves, 256-f half
// each, grid 1568, cross-tile K prefetch, no setprio). Unchanged.
__global__ __launch_bounds__(128) void k4_attn(
    const unsigned short* __restrict__ Qp, const unsigned short* __restrict__ Kp,
    const unsigned short* __restrict__ Vp, float* __restrict__ rw) {
    __shared__ float ebuf[32 * 132];
    int wg = blockIdx.x;
    int bh = wg & 15;                     // wg%8 == bh%8 -> XCD affinity
    int fh = (wg >> 4) & 1;               // feature half
    int qt = wg >> 5;
    int q0 = qt * 32;
    int t = threadIdx.x;
    int w = t >> 6, lane = t & 63;        // w in {0,1}
    int l31 = lane & 31, hh = lane >> 5;

    const unsigned short* __restrict__ Qpb = Qp + ((size_t)(bh * 49 + qt) * 4) * 512 + lane * 8;
    const unsigned short* __restrict__ Kpb = Kp + (size_t)bh * 49 * 2048 + lane * 8;
    const unsigned short* __restrict__ Vpb = Vp + (size_t)bh * 49 * 16384 + lane * 8;
    int wq = fh * 2 + w;                  // quarter index in Vp layout (0..3)

    s16x8 qa0 = *(const s16x8*)&Qpb[0];
    s16x8 qa1 = *(const s16x8*)&Qpb[512];
    s16x8 ql0 = *(const s16x8*)&Qpb[1024];
    s16x8 ql1 = *(const s16x8*)&Qpb[1536];

    // K fragments for tile 0 (cross-tile prefetch registers)
    s16x8 ka0 = *(const s16x8*)&Kpb[0];
    s16x8 ka1 = *(const s16x8*)&Kpb[512];
    s16x8 kl0 = *(const s16x8*)&Kpb[1024];
    s16x8 kl1 = *(const s16x8*)&Kpb[1536];

    float m = -1e30f, lsum = 0.f;
    f32x16 acc[4];
#pragma unroll
    for (int s = 0; s < 4; ++s) acc[s] = (f32x16)0.f;

    for (int kt = 0; kt < NTOT / 32; ++kt) {
        // ---- V fragment loads (consumed last) ----
        const unsigned short* Vtile = Vpb + (size_t)kt * 16384 + (wq * 8) * 512;
        s16x8 va[8];
#pragma unroll
        for (int fr = 0; fr < 8; ++fr)
            va[fr] = *(const s16x8*)&Vtile[fr * 512];
        // ---- prefetch next K tile ----
        int ktn = (kt < 48) ? kt + 1 : 48;
        const unsigned short* Ktn = Kpb + (size_t)ktn * 2048;
        s16x8 kn0 = *(const s16x8*)&Ktn[0];
        s16x8 kn1 = *(const s16x8*)&Ktn[512];
        s16x8 kn2 = *(const s16x8*)&Ktn[1024];
        s16x8 kn3 = *(const s16x8*)&Ktn[1536];

        // ---- S^T = K @ Q^T (32k x 32q), 3-term hi/lo, exp2 domain ----
        f32x16 sacc = (f32x16)0.f;
        sacc = __builtin_amdgcn_mfma_f32_32x32x16_bf16(kl0, qa0, sacc, 0, 0, 0);
        sacc = __builtin_amdgcn_mfma_f32_32x32x16_bf16(ka0, ql0, sacc, 0, 0, 0);
        sacc = __builtin_amdgcn_mfma_f32_32x32x16_bf16(ka0, qa0, sacc, 0, 0, 0);
        sacc = __builtin_amdgcn_mfma_f32_32x32x16_bf16(kl1, qa1, sacc, 0, 0, 0);
        sacc = __builtin_amdgcn_mfma_f32_32x32x16_bf16(ka1, ql1, sacc, 0, 0, 0);
        sacc = __builtin_amdgcn_mfma_f32_32x32x16_bf16(ka1, qa1, sacc, 0, 0, 0);

        // ---- online softmax stats (log2 domain), max3-fused tree ----
        float t0 = fmaxf(fmaxf(sacc[0], sacc[1]), sacc[2]);
        float t1 = fmaxf(fmaxf(sacc[3], sacc[4]), sacc[5]);
        float t2 = fmaxf(fmaxf(sacc[6], sacc[7]), sacc[8]);
        float t3 = fmaxf(fmaxf(sacc[9], sacc[10]), sacc[11]);
        float t4 = fmaxf(fmaxf(sacc[12], sacc[13]), sacc[14]);
        float u0 = fmaxf(fmaxf(t0, t1), t2);
        float u1 = fmaxf(t3, t4);
        float tmax = fmaxf(fmaxf(u0, u1), sacc[15]);
        tmax = fmaxf(tmax, __shfl_xor(tmax, 32, 64));
        if (__any(tmax > m + 11.5f)) {        // defer-max, log2 units (~e^8)
            float mn = fmaxf(m, tmax);
            float sc = fexp2(m - mn);
#pragma unroll
            for (int s = 0; s < 4; ++s) acc[s] = acc[s] * sc;
            lsum *= sc;
            m = mn;
        }
        // ---- P = 2^(S - m) (single v_exp each), pack bf16 pairs ----
        unsigned P2[8];
        float ts0 = 0.f, ts1 = 0.f;
#pragma unroll
        for (int j = 0; j < 8; ++j) {
            float pa = fexp2(sacc[2 * j] - m);
            float pb = fexp2(sacc[2 * j + 1] - m);
            ts0 += pa; ts1 += pb;
            P2[j] = cvt_pk_bf16(pa, pb);
        }
        float tsum = ts0 + ts1;
        lsum += tsum + __shfl_xor(tsum, 32, 64);
        // ---- half-exchange via permlane32_swap ----
        permlane32_swap(P2[0], P2[2]);
        permlane32_swap(P2[1], P2[3]);
        permlane32_swap(P2[4], P2[6]);
        permlane32_swap(P2[5], P2[7]);
        u32x4 b0u, b1u;
        b0u[0] = P2[0]; b0u[1] = P2[1]; b0u[2] = P2[2]; b0u[3] = P2[3];
        b1u[0] = P2[4]; b1u[1] = P2[5]; b1u[2] = P2[6]; b1u[3] = P2[7];
        s16x8 pb0 = __builtin_bit_cast(s16x8, b0u);
        s16x8 pb1 = __builtin_bit_cast(s16x8, b1u);

        // ---- PV: O^T[f][q] += V^T[f][k] P^T[k][q] ----
#pragma unroll
        for (int sub = 0; sub < 4; ++sub) {
            acc[sub] = __builtin_amdgcn_mfma_f32_32x32x16_bf16(va[2 * sub],     pb0, acc[sub], 0, 0, 0);
            acc[sub] = __builtin_amdgcn_mfma_f32_32x32x16_bf16(va[2 * sub + 1], pb1, acc[sub], 0, 0, 0);
        }
        ka0 = kn0; ka1 = kn1; kl0 = kn2; kl1 = kn3;
    }

    // ---- epilogue: normalize, 2-chunk LDS transpose, coalesced store ----
    float inv = 1.f / lsum;
    float* rwg = rw + ((size_t)bh * NTOT + q0) * FDIM + fh * 256;
#pragma unroll
    for (int c = 0; c < 2; ++c) {
        __syncthreads();
        if (w == c) {
#pragma unroll
            for (int sub = 0; sub < 4; ++sub) {
#pragma unroll
                for (int r = 0; r < 16; ++r) {
                    int fl = sub * 32 + (r & 3) + 8 * (r >> 2) + 4 * hh;
                    ebuf[l31 * 132 + fl] = acc[sub][r] * inv;
                }
            }
        }
        __syncthreads();
        int qr = t >> 2, cb = (t & 3) * 32;
#pragma unroll
        for (int j = 0; j < 8; ++j) {
            *(float4*)&rwg[(size_t)qr * FDIM + c * 128 + cb + j * 4] =
                *(const float4*)&ebuf[qr * 132 + cb + j * 4];
        }
    }
}

// ---------------------------------------------------------------------------
// K5: MFMA GEMM per window: out(64n x 256c) = rwL(64n x 64j) @ Wback(64j x 256c)
// R18: staging split uses pair-packed cvt_pk.
__global__ __launch_bounds__(256) void k5_back(
    const float* __restrict__ rw, const unsigned short* __restrict__ Wp,
    float* __restrict__ out) {
    __shared__ unsigned short SB[2 * 64 * 72];   // hi plane, lo plane (18.4 KB)
    unsigned short* BhL = SB;
    unsigned short* BlL = SB + 64 * 72;
    int blk = blockIdx.x;
    int b = blk / NTOT, N = blk % NTOT;
    int src = N / NSRC, nloc = N % NSRC;
    int wh = nloc / 28, ww = nloc % 28;
    int t = threadIdx.x;
    int w = t >> 6, lane = t & 63;
    int lm = lane & 15, lk = lane >> 4;
    int pbase = (b * 224 + wh * 8) * 224 + ww * 8;

#pragma unroll
    for (int i = 0; i < 4; ++i) {
        int flat4 = i * 256 + t;
        int h = flat4 >> 7;
        int f0 = (flat4 & 127) * 4;
        float4 v = *(const float4*)&rw[((size_t)(b * NHD + h) * NTOT + N) * FDIM + f0];
        int n = f0 >> 3;
        int ebase = f0 & 7;
        float vv[4] = {v.x, v.y, v.z, v.w};
#pragma unroll
        for (int p = 0; p < 2; ++p) {
            unsigned wh2, wl2;
            split_pk2(vv[2 * p], vv[2 * p + 1], wh2, wl2);
            int j8a = ebase + 2 * p, j8b = ebase + 2 * p + 1;
            int cola = ((j8a ^ (n & 7)) << 3) | h;
            int colb = ((j8b ^ (n & 7)) << 3) | h;
            BhL[n * 72 + cola] = (unsigned short)wh2;
            BhL[n * 72 + colb] = (unsigned short)(wh2 >> 16);
            BlL[n * 72 + cola] = (unsigned short)wl2;
            BlL[n * 72 + colb] = (unsigned short)(wl2 >> 16);
        }
    }
    __syncthreads();

    f32x4 acc[4][4];
#pragma unroll
    for (int mi = 0; mi < 4; ++mi)
#pragma unroll
        for (int nt = 0; nt < 4; ++nt) acc[mi][nt] = (f32x4)0.f;

    const unsigned short* Wpw = Wp + (size_t)(w * 4) * 2048 + lane * 8;
#pragma unroll
    for (int kc = 0; kc < 2; ++kc) {
        s16x8 Ah[4], Al[4], Bh4[4], Bl4[4];
#pragma unroll
        for (int mi = 0; mi < 4; ++mi) {
            int base = mi * 2048 + kc * 1024;
            Ah[mi] = *(const s16x8*)&Wpw[base];
            Al[mi] = *(const s16x8*)&Wpw[base + 512];
        }
#pragma unroll
        for (int nt = 0; nt < 4; ++nt) {
            int n = nt * 16 + lm;
            int addr = n * 72 + (((kc * 4 + lk) ^ (n & 7)) << 3);
            Bh4[nt] = *(const s16x8*)&BhL[addr];
            Bl4[nt] = *(const s16x8*)&BlL[addr];
        }
#pragma unroll
        for (int mi = 0; mi < 4; ++mi)
#pragma unroll
            for (int nt = 0; nt < 4; ++nt) {
                acc[mi][nt] = __builtin_amdgcn_mfma_f32_16x16x32_bf16(Ah[mi], Bl4[nt], acc[mi][nt], 0, 0, 0);
                acc[mi][nt] = __builtin_amdgcn_mfma_f32_16x16x32_bf16(Al[mi], Bh4[nt], acc[mi][nt], 0, 0, 0);
                acc[mi][nt] = __builtin_amdgcn_mfma_f32_16x16x32_bf16(Ah[mi], Bh4[nt], acc[mi][nt], 0, 0, 0);
            }
    }

    float* eb = (float*)SB;
    float* outp = out + (size_t)src * OUT_PER_SRC;
#pragma unroll
    for (int ch = 0; ch < 4; ++ch) {
        __syncthreads();
        if (w == ch) {
#pragma unroll
            for (int mi = 0; mi < 4; ++mi)
#pragma unroll
                for (int nt = 0; nt < 4; ++nt)
#pragma unroll
                    for (int r = 0; r < 4; ++r) {
                        int n = nt * 16 + lm;
                        int cl = mi * 16 + lk * 4 + r;
                        eb[n * 68 + cl] = acc[mi][nt][r];
                    }
        }
        __syncthreads();
#pragma unroll
        for (int i = 0; i < 4; ++i) {
            int fl4 = i * 256 + t;
            int n = fl4 >> 4, c4 = (fl4 & 15) * 4;
            int opix = pbase + (n >> 3) * 224 + (n & 7);
            *(float4*)&outp[(size_t)opix * DVC + ch * 64 + c4] =
                *(const float4*)&eb[n * 68 + c4];
        }
    }
}

// ---------------------------------------------------------------------------
extern "C" void kernel_launch(void* const* d_in, const int* in_sizes, int n_in,
                              void* d_out, int out_size, void* d_ws, size_t ws_size,
                              hipStream_t stream) {
    const float* v0   = (const float*)d_in[0];
    const float* c0   = (const float*)d_in[1];
    const float* v1   = (const float*)d_in[2];
    const float* c1   = (const float*)d_in[3];
    const float* Wqkv = (const float*)d_in[4];
    const float* bqkv = (const float*)d_in[5];
    const float* gv   = (const float*)d_in[6];
    const float* Wqkc = (const float*)d_in[7];
    const float* bqkc = (const float*)d_in[8];
    const float* gc   = (const float*)d_in[9];
    const float* Wv   = (const float*)d_in[10];
    const float* Wbk  = (const float*)d_in[11];

    float* ws = (float*)d_ws;
    float* rw   = ws;                        // 12,845,056 fl (aliases Vavg/Cavg)
    float* Vavg = ws;                        //    802,816 fl
    float* Cavg = ws + 802816;               //    200,704 fl
    unsigned short* Qp   = (unsigned short*)(ws + 12845056);  // 1,605,632 u16
    unsigned short* Kp   = (unsigned short*)(ws + 13647872);  // 1,605,632 u16
    unsigned short* Wvp  = (unsigned short*)(ws + 14450688);  //    32,768 u16
    unsigned short* Vvb  = (unsigned short*)(ws + 14467072);  // 12,845,056 u16
    unsigned short* Vp   = (unsigned short*)(ws + 20889600);  // 12,845,056 u16
    unsigned short* Wp   = (unsigned short*)(ws + 27312128);  //    65,536 u16
    // total ends at 27,344,896 fl = 109.4 MB

    float* outp = (float*)d_out;

    kz_zero   <<<1568, 256, 0, stream>>>(Qp);   // zeros Qp+Kp (contiguous)
    k0c_wvpack<<<256, 256, 0, stream>>>(Wv, Wvp);
    k0b_wback <<<256, 256, 0, stream>>>(Wbk, Wp);
    k3_vv     <<<2 * NTOT, 256, 0, stream>>>(v0, v1, Wvp, Vvb, Vavg);
    k1c_avg   <<<784, 256, 0, stream>>>(c0, c1, Cavg);
    k2_qk     <<<2 * NTOT, 256, 0, stream>>>(Vavg, Cavg, Wqkv, bqkv, gv, Wqkc, bqkc, gc, Qp, Kp);
    k3b_pack  <<<dim3(49, 16), 256, 0, stream>>>(Vvb, Vp);
    k4_attn   <<<1568, 128, 0, stream>>>(Qp, Kp, Vp, rw);
    k5_back   <<<2 * NTOT, 256, 0, stream>>>(rw, Wp, outp);
}

// Round 19
// 316.571 us; speedup vs baseline: 1.1398x; 1.0339x over previous
//
#include <hip/hip_runtime.h>

#define NSRC 784
#define NTOT 1568
#define NHD 8
#define DVC 256
#define DCC 64
#define D20 20
#define FDIM 512
#define OUT_PER_SRC 25690112

typedef short s16x8 __attribute__((ext_vector_type(8)));
typedef unsigned short u16x8 __attribute__((ext_vector_type(8)));
typedef unsigned short u16x4 __attribute__((ext_vector_type(4)));
typedef float f32x4 __attribute__((ext_vector_type(4)));
typedef float f32x16 __attribute__((ext_vector_type(16)));
typedef unsigned u32x4 __attribute__((ext_vector_type(4)));

#define LOG2E 1.4426950408889634f

__device__ __forceinline__ unsigned short f2bf(float x) {
    unsigned u = __float_as_uint(x);
    unsigned r = (u + 0x7FFFu + ((u >> 16) & 1u)) >> 16;   // RNE
    return (unsigned short)r;
}

__device__ __forceinline__ unsigned cvt_pk_bf16(float lo, float hi) {
    unsigned r;
    asm volatile("v_cvt_pk_bf16_f32 %0, %1, %2" : "=v"(r) : "v"(lo), "v"(hi));
    return r;
}

// native 2^x (single v_exp_f32, no libcall guards, no pre-multiply)
__device__ __forceinline__ float fexp2(float x) {
    float r;
    asm("v_exp_f32 %0, %1" : "=v"(r) : "v"(x));
    return r;
}

// split float into bf16 hi + bf16 lo correction (x ~= hi + lo)
__device__ __forceinline__ void split_bf(float x, unsigned short& hi, unsigned short& lo) {
    unsigned short h = f2bf(x);
    float hf = __uint_as_float(((unsigned)h) << 16);
    hi = h;
    lo = f2bf(x - hf);
}

// pair split via v_cvt_pk: wh = packed bf16 hi of (x0,x1); wl = packed lo
// residuals. Identity x ~= hif + lof holds for any hi rounding.
__device__ __forceinline__ void split_pk2(float x0, float x1,
                                          unsigned& wh, unsigned& wl) {
    wh = cvt_pk_bf16(x0, x1);
    float h0 = __uint_as_float(wh << 16);
    float h1 = __uint_as_float(wh & 0xffff0000u);
    wl = cvt_pk_bf16(x0 - h0, x1 - h1);
}

// v_permlane32_swap_b32: a' = [a.lo32 | b.lo32], b' = [a.hi32 | b.hi32]
__device__ __forceinline__ void permlane32_swap(unsigned& a, unsigned& b) {
    asm volatile("v_permlane32_swap_b32 %0, %1" : "+v"(a), "+v"(b));
}

// ---------------------------------------------------------------------------
// KZ: zero Qp+Kp (contiguous) — clears the d in [20,32) pad slots
__global__ __launch_bounds__(256) void kz_zero(unsigned short* __restrict__ p) {
    size_t i = (size_t)blockIdx.x * 256 + threadIdx.x;
    u16x8 z = (u16x8)0;
    *(u16x8*)&p[i * 8] = z;
}

// ---------------------------------------------------------------------------
// K0c: pack Wv(256dd x 64e) -> A-fragment order hi/lo for k3
__global__ __launch_bounds__(256) void k0c_wvpack(
    const float* __restrict__ Wv, unsigned short* __restrict__ Wvp) {
    int idx = blockIdx.x * 256 + threadIdx.x;        // 0..65535
    int j = idx & 7, lane = (idx >> 3) & 63, hl = (idx >> 9) & 1;
    int c = (idx >> 10) & 7, mi = idx >> 13;
    int e = mi * 16 + (lane & 15);
    int dd = c * 32 + (lane >> 4) * 8 + j;
    unsigned short h, l;
    split_bf(Wv[dd * DCC + e], h, l);
    Wvp[idx] = hl ? l : h;
}

// ---------------------------------------------------------------------------
// K0b: pack Wback(64j x 256c) -> A-fragment order hi/lo
__global__ __launch_bounds__(256) void k0b_wback(
    const float* __restrict__ Wb, unsigned short* __restrict__ Wp) {
    int idx = blockIdx.x * 256 + threadIdx.x;        // 0..65535
    int jj = idx & 7, lane = (idx >> 3) & 63, hl = (idx >> 9) & 1;
    int kc = (idx >> 10) & 1, mt = idx >> 11;
    int c = mt * 16 + (lane & 15);
    int j = kc * 32 + (lane >> 4) * 8 + jj;
    unsigned short h, l;
    split_bf(Wb[j * 256 + c], h, l);
    Wp[idx] = hl ? l : h;
}

// ---------------------------------------------------------------------------
// K1c: window average of coords only
__global__ __launch_bounds__(256) void k1c_avg(
    const float* __restrict__ c0, const float* __restrict__ c1,
    float* __restrict__ Cavg) {
    int wi = blockIdx.x * 4 + (threadIdx.x >> 6);
    int d = threadIdx.x & 63;
    int b = wi / NTOT, N = wi % NTOT;
    int src = N / NSRC, nloc = N % NSRC;
    int wh = nloc / 28, ww = nloc % 28;
    const float* __restrict__ C = src ? c1 : c0;
    int pbase = (b * 224 + wh * 8) * 224 + ww * 8;
    float s = 0.f;
#pragma unroll 8
    for (int p = 0; p < 64; ++p)
        s += C[(size_t)(pbase + (p >> 3) * 224 + (p & 7)) * DCC + d];
    Cavg[(size_t)wi * DCC + d] = s * 0.015625f;
}

// ---------------------------------------------------------------------------
// K2: qk = rmsnorm(avg @ Wqk + b, g); R19: 4 windows per block — W column
// loads amortized x4 (L2 traffic 802 -> 200 MB). Writes Q/K bf16 hi/lo
// fragments in k4's packed lane order; Q pre-scaled by log2(e)/sqrt(I).
__global__ __launch_bounds__(256) void k2_qk(
    const float* __restrict__ Vavg, const float* __restrict__ Cavg,
    const float* __restrict__ Wqkv, const float* __restrict__ bqkv, const float* __restrict__ gv,
    const float* __restrict__ Wqkc, const float* __restrict__ bqkc, const float* __restrict__ gc,
    unsigned short* __restrict__ Qp, unsigned short* __restrict__ Kp) {
    __shared__ float xv[4][DVC];
    __shared__ float xc[4][DCC];
    __shared__ float wred[4][4];
    int blk4 = blockIdx.x;                 // 0..783, rows blk4*4..+3
    int t = threadIdx.x;
    // load 4 rows of Vavg (4*256 floats) and Cavg (4*64)
#pragma unroll
    for (int r = 0; r < 4; ++r)
        xv[r][t] = Vavg[((size_t)blk4 * 4 + r) * DVC + t];
    if (t < 4 * DCC) xc[t >> 6][t & 63] = Cavg[(size_t)blk4 * 4 * DCC + t];
    __syncthreads();

    float yv[4];
#pragma unroll
    for (int r = 0; r < 4; ++r) yv[r] = bqkv[t];
#pragma unroll 4
    for (int d = 0; d < DVC; ++d) {
        float wv = Wqkv[d * 256 + t];
#pragma unroll
        for (int r = 0; r < 4; ++r) yv[r] += xv[r][d] * wv;
    }
#pragma unroll
    for (int r = 0; r < 4; ++r) {
        float ss = yv[r] * yv[r];
#pragma unroll
        for (int off = 32; off; off >>= 1) ss += __shfl_xor(ss, off, 64);
        if ((t & 63) == 0) wred[r][t >> 6] = ss;
    }
    __syncthreads();
    int h = t >> 5, c = t & 31;
    int isq = (c < 16);
    int d = isq ? c : c - 16;
    int hh = d >> 3, j = d & 7;
    unsigned short* dst = isq ? Qp : Kp;
    float g = gv[t];
#pragma unroll
    for (int r = 0; r < 4; ++r) {
        int blk = blk4 * 4 + r;
        int b = blk / NTOT, N = blk % NTOT;
        int tile = N >> 5, l31 = N & 31;
        int bh = b * NHD + h;
        float tot = wred[r][0] + wred[r][1] + wred[r][2] + wred[r][3];
        float rv = rsqrtf(tot * (1.f / 256.f) + 1e-6f);
        float yn = yv[r] * rv * g;
        float val = isq ? yn * (0.088388347648318447f * LOG2E) : yn;
        unsigned short h16, l16;
        split_bf(val, h16, l16);
        size_t base = ((size_t)(bh * 49 + tile) * 4) * 512 + (size_t)(hh * 32 + l31) * 8 + j;
        dst[base] = h16;
        dst[base + 1024] = l16;
    }
    if (t < DCC) {
        float yc[4];
#pragma unroll
        for (int r = 0; r < 4; ++r) yc[r] = bqkc[t];
#pragma unroll 4
        for (int dd2 = 0; dd2 < DCC; ++dd2) {
            float wc = Wqkc[dd2 * 64 + t];
#pragma unroll
            for (int r = 0; r < 4; ++r) yc[r] += xc[r][dd2] * wc;
        }
        int h2 = t >> 3, c2 = t & 7;
        int isq2 = (c2 < 4);
        int dd = isq2 ? c2 : c2 - 4;
        unsigned short* dst2 = isq2 ? Qp : Kp;
        float g2 = gc[t];
#pragma unroll
        for (int r = 0; r < 4; ++r) {
            float sc = yc[r] * yc[r];
#pragma unroll
            for (int off = 32; off; off >>= 1) sc += __shfl_xor(sc, off, 64);
            float rc = rsqrtf(sc * (1.f / 64.f) + 1e-6f);
            float ycn = yc[r] * rc * g2;
            int blk = blk4 * 4 + r;
            int b = blk / NTOT, N = blk % NTOT;
            int tile = N >> 5, l31 = N & 31;
            int bh2 = b * NHD + h2;
            float val = isq2 ? ycn * (0.17677669529663687f * LOG2E) : ycn;
            unsigned short h16, l16;
            split_bf(val, h16, l16);
            size_t base = ((size_t)(bh2 * 49 + tile) * 4 + 1) * 512 + (size_t)l31 * 8 + dd;
            dst2[base] = h16;
            dst2[base + 1024] = l16;
        }
    }
}

// ---------------------------------------------------------------------------
// K3: per-window GEMM as D[e][px] = W^T @ X^T — zero-LDS, zero-barrier main
// loop. Pair-packed hi/lo split via v_cvt_pk. (unchanged from R18)
__global__ __launch_bounds__(256) void k3_vv(
    const float* __restrict__ v0, const float* __restrict__ v1,
    const unsigned short* __restrict__ Wvp,
    unsigned short* __restrict__ Vvb, float* __restrict__ Vavg) {
    __shared__ unsigned short eb[64 * 66];   // 8.4 KB
    __shared__ float avgw[1024];             // 4 KB
    int blk = blockIdx.x;
    int b = blk / NTOT, N = blk % NTOT;
    int src = N / NSRC, nloc = N % NSRC;
    int wh = nloc / 28, ww = nloc % 28;
    const float* __restrict__ V = src ? v1 : v0;
    int t = threadIdx.x;
    int w = t >> 6, lane = t & 63;
    int lm = lane & 15, lk = lane >> 4;
    int px = w * 16 + lm;
    int pbase = (b * 224 + wh * 8) * 224 + ww * 8;
    const float* __restrict__ xrow =
        V + (size_t)(pbase + (px >> 3) * 224 + (px & 7)) * DVC + lk * 8;

    f32x4 acc[4];
#pragma unroll
    for (int mi = 0; mi < 4; ++mi) acc[mi] = (f32x4)0.f;

#pragma unroll
    for (int c = 0; c < 8; ++c) {
        float4 x0 = *(const float4*)&xrow[c * 32];
        float4 x1 = *(const float4*)&xrow[c * 32 + 4];
        float xv8[8] = {x0.x, x0.y, x0.z, x0.w, x1.x, x1.y, x1.z, x1.w};
        u32x4 hw, lw;
#pragma unroll
        for (int p = 0; p < 4; ++p) {
            unsigned wh2, wl2;
            split_pk2(xv8[2 * p], xv8[2 * p + 1], wh2, wl2);
            hw[p] = wh2; lw[p] = wl2;
        }
        s16x8 xhi = __builtin_bit_cast(s16x8, hw);
        s16x8 xlo = __builtin_bit_cast(s16x8, lw);
        float sv[8] = {xv8[0], xv8[1], xv8[2], xv8[3], xv8[4], xv8[5], xv8[6], xv8[7]};
#pragma unroll
        for (int off = 1; off <= 8; off <<= 1)
#pragma unroll
            for (int j = 0; j < 8; ++j) sv[j] += __shfl_xor(sv[j], off, 64);
        if (lm == 0) {
#pragma unroll
            for (int j = 0; j < 8; ++j)
                avgw[w * 256 + c * 32 + lk * 8 + j] = sv[j];
        }
#pragma unroll
        for (int mi = 0; mi < 4; ++mi) {
            const unsigned short* Wf = Wvp + (size_t)((mi * 8 + c) * 2) * 512 + lane * 8;
            s16x8 Ah = *(const s16x8*)&Wf[0];
            s16x8 Al = *(const s16x8*)&Wf[512];
            acc[mi] = __builtin_amdgcn_mfma_f32_16x16x32_bf16(Ah, xlo, acc[mi], 0, 0, 0);
            acc[mi] = __builtin_amdgcn_mfma_f32_16x16x32_bf16(Al, xhi, acc[mi], 0, 0, 0);
            acc[mi] = __builtin_amdgcn_mfma_f32_16x16x32_bf16(Ah, xhi, acc[mi], 0, 0, 0);
        }
    }
#pragma unroll
    for (int mi = 0; mi < 4; ++mi) {
#pragma unroll
        for (int r = 0; r < 4; ++r) {
            int e = mi * 16 + lk * 4 + r;
            eb[px * 66 + e] = f2bf(acc[mi][r]);
        }
    }
    __syncthreads();
    unsigned short* dst = Vvb + (size_t)blk * 4096;
#pragma unroll
    for (int i = 0; i < 2; ++i) {
        int flat16 = i * 256 + t;            // 0..511
        int f3 = flat16 >> 6;
        int h = (flat16 >> 3) & 7;
        int px8 = (flat16 & 7) * 8;
        u16x8 vv;
#pragma unroll
        for (int u = 0; u < 8; ++u) vv[u] = eb[(px8 + u) * 66 + f3 * 8 + h];
        *(u16x8*)&dst[flat16 * 8] = vv;
    }
    Vavg[(size_t)blk * DVC + t] =
        (avgw[t] + avgw[256 + t] + avgw[512 + t] + avgw[768 + t]) * 0.015625f;
}

// ---------------------------------------------------------------------------
// K3b: pack Vvb [b][N][f3][h][px] -> Vp fragment order (unchanged)
__global__ __launch_bounds__(256) void k3b_pack(
    const unsigned short* __restrict__ Vvb, unsigned short* __restrict__ Vp) {
    __shared__ unsigned short tile[32 * 576];   // [N][f3][72]
    int kt = blockIdx.x, bh = blockIdx.y;
    int b = bh >> 3, h = bh & 7;
    int t = threadIdx.x;
#pragma unroll
    for (int it = 0; it < 8; ++it) {
        int flat = it * 256 + t;                // 0..2047
        int r5 = flat >> 6;
        int c = flat & 63;
        int f3 = c >> 3, px8 = (c & 7) * 8;
        const unsigned short* s =
            Vvb + ((size_t)(b * NTOT + kt * 32 + r5) * 8 + f3) * 512 + h * 64 + px8;
        *(u16x8*)&tile[r5 * 576 + f3 * 72 + px8] = *(const u16x8*)s;
    }
    __syncthreads();
    unsigned short* dst = Vp + ((size_t)bh * 49 + kt) * 16384;
#pragma unroll
    for (int it = 0; it < 8; ++it) {
        int flato = it * 256 + t;
        int lane = flato & 63;
        int kh = (flato >> 6) & 1;
        int sub = (flato >> 7) & 3;
        int w = flato >> 9;
        int l31 = lane & 31, hh = lane >> 5;
        int f = w * 128 + sub * 32 + l31;
        int kbase = kh * 16 + hh * 8;
        u16x8 v;
#pragma unroll
        for (int j = 0; j < 8; ++j)
            v[j] = tile[(kbase + j) * 576 + (f & 7) * 72 + (f >> 3)];
        *(u16x8*)&dst[(size_t)flato * 8] = v;
    }
}

// ---------------------------------------------------------------------------
// K4: flash attention — R17 structure (128-thread blocks, 2 waves, 256-f half
// each, grid 1568, cross-tile K prefetch, no setprio). Unchanged.
__global__ __launch_bounds__(128) void k4_attn(
    const unsigned short* __restrict__ Qp, const unsigned short* __restrict__ Kp,
    const unsigned short* __restrict__ Vp, float* __restrict__ rw) {
    __shared__ float ebuf[32 * 132];
    int wg = blockIdx.x;
    int bh = wg & 15;                     // wg%8 == bh%8 -> XCD affinity
    int fh = (wg >> 4) & 1;               // feature half
    int qt = wg >> 5;
    int q0 = qt * 32;
    int t = threadIdx.x;
    int w = t >> 6, lane = t & 63;        // w in {0,1}
    int l31 = lane & 31, hh = lane >> 5;

    const unsigned short* __restrict__ Qpb = Qp + ((size_t)(bh * 49 + qt) * 4) * 512 + lane * 8;
    const unsigned short* __restrict__ Kpb = Kp + (size_t)bh * 49 * 2048 + lane * 8;
    const unsigned short* __restrict__ Vpb = Vp + (size_t)bh * 49 * 16384 + lane * 8;
    int wq = fh * 2 + w;                  // quarter index in Vp layout (0..3)

    s16x8 qa0 = *(const s16x8*)&Qpb[0];
    s16x8 qa1 = *(const s16x8*)&Qpb[512];
    s16x8 ql0 = *(const s16x8*)&Qpb[1024];
    s16x8 ql1 = *(const s16x8*)&Qpb[1536];

    // K fragments for tile 0 (cross-tile prefetch registers)
    s16x8 ka0 = *(const s16x8*)&Kpb[0];
    s16x8 ka1 = *(const s16x8*)&Kpb[512];
    s16x8 kl0 = *(const s16x8*)&Kpb[1024];
    s16x8 kl1 = *(const s16x8*)&Kpb[1536];

    float m = -1e30f, lsum = 0.f;
    f32x16 acc[4];
#pragma unroll
    for (int s = 0; s < 4; ++s) acc[s] = (f32x16)0.f;

    for (int kt = 0; kt < NTOT / 32; ++kt) {
        // ---- V fragment loads (consumed last) ----
        const unsigned short* Vtile = Vpb + (size_t)kt * 16384 + (wq * 8) * 512;
        s16x8 va[8];
#pragma unroll
        for (int fr = 0; fr < 8; ++fr)
            va[fr] = *(const s16x8*)&Vtile[fr * 512];
        // ---- prefetch next K tile ----
        int ktn = (kt < 48) ? kt + 1 : 48;
        const unsigned short* Ktn = Kpb + (size_t)ktn * 2048;
        s16x8 kn0 = *(const s16x8*)&Ktn[0];
        s16x8 kn1 = *(const s16x8*)&Ktn[512];
        s16x8 kn2 = *(const s16x8*)&Ktn[1024];
        s16x8 kn3 = *(const s16x8*)&Ktn[1536];

        // ---- S^T = K @ Q^T (32k x 32q), 3-term hi/lo, exp2 domain ----
        f32x16 sacc = (f32x16)0.f;
        sacc = __builtin_amdgcn_mfma_f32_32x32x16_bf16(kl0, qa0, sacc, 0, 0, 0);
        sacc = __builtin_amdgcn_mfma_f32_32x32x16_bf16(ka0, ql0, sacc, 0, 0, 0);
        sacc = __builtin_amdgcn_mfma_f32_32x32x16_bf16(ka0, qa0, sacc, 0, 0, 0);
        sacc = __builtin_amdgcn_mfma_f32_32x32x16_bf16(kl1, qa1, sacc, 0, 0, 0);
        sacc = __builtin_amdgcn_mfma_f32_32x32x16_bf16(ka1, ql1, sacc, 0, 0, 0);
        sacc = __builtin_amdgcn_mfma_f32_32x32x16_bf16(ka1, qa1, sacc, 0, 0, 0);

        // ---- online softmax stats (log2 domain), max3-fused tree ----
        float t0 = fmaxf(fmaxf(sacc[0], sacc[1]), sacc[2]);
        float t1 = fmaxf(fmaxf(sacc[3], sacc[4]), sacc[5]);
        float t2 = fmaxf(fmaxf(sacc[6], sacc[7]), sacc[8]);
        float t3 = fmaxf(fmaxf(sacc[9], sacc[10]), sacc[11]);
        float t4 = fmaxf(fmaxf(sacc[12], sacc[13]), sacc[14]);
        float u0 = fmaxf(fmaxf(t0, t1), t2);
        float u1 = fmaxf(t3, t4);
        float tmax = fmaxf(fmaxf(u0, u1), sacc[15]);
        tmax = fmaxf(tmax, __shfl_xor(tmax, 32, 64));
        if (__any(tmax > m + 11.5f)) {        // defer-max, log2 units (~e^8)
            float mn = fmaxf(m, tmax);
            float sc = fexp2(m - mn);
#pragma unroll
            for (int s = 0; s < 4; ++s) acc[s] = acc[s] * sc;
            lsum *= sc;
            m = mn;
        }
        // ---- P = 2^(S - m) (single v_exp each), pack bf16 pairs ----
        unsigned P2[8];
        float ts0 = 0.f, ts1 = 0.f;
#pragma unroll
        for (int j = 0; j < 8; ++j) {
            float pa = fexp2(sacc[2 * j] - m);
            float pb = fexp2(sacc[2 * j + 1] - m);
            ts0 += pa; ts1 += pb;
            P2[j] = cvt_pk_bf16(pa, pb);
        }
        float tsum = ts0 + ts1;
        lsum += tsum + __shfl_xor(tsum, 32, 64);
        // ---- half-exchange via permlane32_swap ----
        permlane32_swap(P2[0], P2[2]);
        permlane32_swap(P2[1], P2[3]);
        permlane32_swap(P2[4], P2[6]);
        permlane32_swap(P2[5], P2[7]);
        u32x4 b0u, b1u;
        b0u[0] = P2[0]; b0u[1] = P2[1]; b0u[2] = P2[2]; b0u[3] = P2[3];
        b1u[0] = P2[4]; b1u[1] = P2[5]; b1u[2] = P2[6]; b1u[3] = P2[7];
        s16x8 pb0 = __builtin_bit_cast(s16x8, b0u);
        s16x8 pb1 = __builtin_bit_cast(s16x8, b1u);

        // ---- PV: O^T[f][q] += V^T[f][k] P^T[k][q] ----
#pragma unroll
        for (int sub = 0; sub < 4; ++sub) {
            acc[sub] = __builtin_amdgcn_mfma_f32_32x32x16_bf16(va[2 * sub],     pb0, acc[sub], 0, 0, 0);
            acc[sub] = __builtin_amdgcn_mfma_f32_32x32x16_bf16(va[2 * sub + 1], pb1, acc[sub], 0, 0, 0);
        }
        ka0 = kn0; ka1 = kn1; kl0 = kn2; kl1 = kn3;
    }

    // ---- epilogue: normalize, 2-chunk LDS transpose, coalesced store ----
    float inv = 1.f / lsum;
    float* rwg = rw + ((size_t)bh * NTOT + q0) * FDIM + fh * 256;
#pragma unroll
    for (int c = 0; c < 2; ++c) {
        __syncthreads();
        if (w == c) {
#pragma unroll
            for (int sub = 0; sub < 4; ++sub) {
#pragma unroll
                for (int r = 0; r < 16; ++r) {
                    int fl = sub * 32 + (r & 3) + 8 * (r >> 2) + 4 * hh;
                    ebuf[l31 * 132 + fl] = acc[sub][r] * inv;
                }
            }
        }
        __syncthreads();
        int qr = t >> 2, cb = (t & 3) * 32;
#pragma unroll
        for (int j = 0; j < 8; ++j) {
            *(float4*)&rwg[(size_t)qr * FDIM + c * 128 + cb + j * 4] =
                *(const float4*)&ebuf[qr * 132 + cb + j * 4];
        }
    }
}

// ---------------------------------------------------------------------------
// K5: MFMA GEMM per window: out(64n x 256c) = rwL(64n x 64j) @ Wback(64j x 256c)
// Pair-packed cvt_pk staging. (unchanged from R18)
__global__ __launch_bounds__(256) void k5_back(
    const float* __restrict__ rw, const unsigned short* __restrict__ Wp,
    float* __restrict__ out) {
    __shared__ unsigned short SB[2 * 64 * 72];   // hi plane, lo plane (18.4 KB)
    unsigned short* BhL = SB;
    unsigned short* BlL = SB + 64 * 72;
    int blk = blockIdx.x;
    int b = blk / NTOT, N = blk % NTOT;
    int src = N / NSRC, nloc = N % NSRC;
    int wh = nloc / 28, ww = nloc % 28;
    int t = threadIdx.x;
    int w = t >> 6, lane = t & 63;
    int lm = lane & 15, lk = lane >> 4;
    int pbase = (b * 224 + wh * 8) * 224 + ww * 8;

#pragma unroll
    for (int i = 0; i < 4; ++i) {
        int flat4 = i * 256 + t;
        int h = flat4 >> 7;
        int f0 = (flat4 & 127) * 4;
        float4 v = *(const float4*)&rw[((size_t)(b * NHD + h) * NTOT + N) * FDIM + f0];
        int n = f0 >> 3;
        int ebase = f0 & 7;
        float vv[4] = {v.x, v.y, v.z, v.w};
#pragma unroll
        for (int p = 0; p < 2; ++p) {
            unsigned wh2, wl2;
            split_pk2(vv[2 * p], vv[2 * p + 1], wh2, wl2);
            int j8a = ebase + 2 * p, j8b = ebase + 2 * p + 1;
            int cola = ((j8a ^ (n & 7)) << 3) | h;
            int colb = ((j8b ^ (n & 7)) << 3) | h;
            BhL[n * 72 + cola] = (unsigned short)wh2;
            BhL[n * 72 + colb] = (unsigned short)(wh2 >> 16);
            BlL[n * 72 + cola] = (unsigned short)wl2;
            BlL[n * 72 + colb] = (unsigned short)(wl2 >> 16);
        }
    }
    __syncthreads();

    f32x4 acc[4][4];
#pragma unroll
    for (int mi = 0; mi < 4; ++mi)
#pragma unroll
        for (int nt = 0; nt < 4; ++nt) acc[mi][nt] = (f32x4)0.f;

    const unsigned short* Wpw = Wp + (size_t)(w * 4) * 2048 + lane * 8;
#pragma unroll
    for (int kc = 0; kc < 2; ++kc) {
        s16x8 Ah[4], Al[4], Bh4[4], Bl4[4];
#pragma unroll
        for (int mi = 0; mi < 4; ++mi) {
            int base = mi * 2048 + kc * 1024;
            Ah[mi] = *(const s16x8*)&Wpw[base];
            Al[mi] = *(const s16x8*)&Wpw[base + 512];
        }
#pragma unroll
        for (int nt = 0; nt < 4; ++nt) {
            int n = nt * 16 + lm;
            int addr = n * 72 + (((kc * 4 + lk) ^ (n & 7)) << 3);
            Bh4[nt] = *(const s16x8*)&BhL[addr];
            Bl4[nt] = *(const s16x8*)&BlL[addr];
        }
#pragma unroll
        for (int mi = 0; mi < 4; ++mi)
#pragma unroll
            for (int nt = 0; nt < 4; ++nt) {
                acc[mi][nt] = __builtin_amdgcn_mfma_f32_16x16x32_bf16(Ah[mi], Bl4[nt], acc[mi][nt], 0, 0, 0);
                acc[mi][nt] = __builtin_amdgcn_mfma_f32_16x16x32_bf16(Al[mi], Bh4[nt], acc[mi][nt], 0, 0, 0);
                acc[mi][nt] = __builtin_amdgcn_mfma_f32_16x16x32_bf16(Ah[mi], Bh4[nt], acc[mi][nt], 0, 0, 0);
            }
    }

    float* eb = (float*)SB;
    float* outp = out + (size_t)src * OUT_PER_SRC;
#pragma unroll
    for (int ch = 0; ch < 4; ++ch) {
        __syncthreads();
        if (w == ch) {
#pragma unroll
            for (int mi = 0; mi < 4; ++mi)
#pragma unroll
                for (int nt = 0; nt < 4; ++nt)
#pragma unroll
                    for (int r = 0; r < 4; ++r) {
                        int n = nt * 16 + lm;
                        int cl = mi * 16 + lk * 4 + r;
                        eb[n * 68 + cl] = acc[mi][nt][r];
                    }
        }
        __syncthreads();
#pragma unroll
        for (int i = 0; i < 4; ++i) {
            int fl4 = i * 256 + t;
            int n = fl4 >> 4, c4 = (fl4 & 15) * 4;
            int opix = pbase + (n >> 3) * 224 + (n & 7);
            *(float4*)&outp[(size_t)opix * DVC + ch * 64 + c4] =
                *(const float4*)&eb[n * 68 + c4];
        }
    }
}

// ---------------------------------------------------------------------------
extern "C" void kernel_launch(void* const* d_in, const int* in_sizes, int n_in,
                              void* d_out, int out_size, void* d_ws, size_t ws_size,
                              hipStream_t stream) {
    const float* v0   = (const float*)d_in[0];
    const float* c0   = (const float*)d_in[1];
    const float* v1   = (const float*)d_in[2];
    const float* c1   = (const float*)d_in[3];
    const float* Wqkv = (const float*)d_in[4];
    const float* bqkv = (const float*)d_in[5];
    const float* gv   = (const float*)d_in[6];
    const float* Wqkc = (const float*)d_in[7];
    const float* bqkc = (const float*)d_in[8];
    const float* gc   = (const float*)d_in[9];
    const float* Wv   = (const float*)d_in[10];
    const float* Wbk  = (const float*)d_in[11];

    float* ws = (float*)d_ws;
    float* rw   = ws;                        // 12,845,056 fl (aliases Vavg/Cavg)
    float* Vavg = ws;                        //    802,816 fl
    float* Cavg = ws + 802816;               //    200,704 fl
    unsigned short* Qp   = (unsigned short*)(ws + 12845056);  // 1,605,632 u16
    unsigned short* Kp   = (unsigned short*)(ws + 13647872);  // 1,605,632 u16
    unsigned short* Wvp  = (unsigned short*)(ws + 14450688);  //    32,768 u16
    unsigned short* Vvb  = (unsigned short*)(ws + 14467072);  // 12,845,056 u16
    unsigned short* Vp   = (unsigned short*)(ws + 20889600);  // 12,845,056 u16
    unsigned short* Wp   = (unsigned short*)(ws + 27312128);  //    65,536 u16
    // total ends at 27,344,896 fl = 109.4 MB

    float* outp = (float*)d_out;

    kz_zero   <<<1568, 256, 0, stream>>>(Qp);   // zeros Qp+Kp (contiguous)
    k0c_wvpack<<<256, 256, 0, stream>>>(Wv, Wvp);
    k0b_wback <<<256, 256, 0, stream>>>(Wbk, Wp);
    k3_vv     <<<2 * NTOT, 256, 0, stream>>>(v0, v1, Wvp, Vvb, Vavg);
    k1c_avg   <<<784, 256, 0, stream>>>(c0, c1, Cavg);
    k2_qk     <<<784, 256, 0, stream>>>(Vavg, Cavg, Wqkv, bqkv, gv, Wqkc, bqkc, gc, Qp, Kp);
    k3b_pack  <<<dim3(49, 16), 256, 0, stream>>>(Vvb, Vp);
    k4_attn   <<<1568, 128, 0, stream>>>(Qp, Kp, Vp, rw);
    k5_back   <<<2 * NTOT, 256, 0, stream>>>(rw, Wp, outp);
}